// Round 1
// baseline (3229.614 us; speedup 1.0000x reference)
//
#include <hip/hip_runtime.h>

#define DD 128
#define KK 20
#define RPB 4

// ---------------------------------------------------------------------------
// Per-group kernel: computes h[n,m,:] for m=0..2 (aggregators, or session
// passthrough when nb2==nullptr && m==2).
//  STORE_H: write h rows to ws h-buffer
//  DO_W   : compute w[n,m] = tanh(h@Ws+bs)@q, block-reduce, atomicAdd to wsum
//  DO_OUT : accumulate out[n,:] = sum_m beta[m]*h[n,m,:] (recompute path)
// block = 128 threads (one output column each), RPB rows per block.
// ---------------------------------------------------------------------------

__device__ __forceinline__ float wave_reduce_sum(float v) {
#pragma unroll
  for (int off = 32; off > 0; off >>= 1) v += __shfl_down(v, off, 64);
  return v;
}

template <bool STORE_H, bool DO_W, bool DO_OUT>
__global__ __launch_bounds__(128)
void k_group(int N, int row_base,
             const int* __restrict__ self_idx, const float* __restrict__ self_emb,
             const int* __restrict__ nb0, const float* __restrict__ emb0,
             const float* __restrict__ W0, const float* __restrict__ b0,
             const int* __restrict__ nb1, const float* __restrict__ emb1,
             const float* __restrict__ W1, const float* __restrict__ b1,
             const int* __restrict__ nb2, const float* __restrict__ emb2,
             const float* __restrict__ W2, const float* __restrict__ b2,
             const float* __restrict__ session,
             const float* __restrict__ Ws, const float* __restrict__ bs,
             const float* __restrict__ q,
             float* __restrict__ h_store,
             float* __restrict__ wsum,
             const float* __restrict__ beta,
             float* __restrict__ out) {
  __shared__ __align__(16) float xs[RPB][2 * DD];  // [row][ self(128) | agg(128) ]
  __shared__ __align__(16) float hs[RPB][DD];
  __shared__ float red[2][RPB];
  __shared__ int iid[RPB];

  const int tid = threadIdx.x;
  const int n0 = blockIdx.x * RPB;

  if (tid < RPB) iid[tid] = self_idx[n0 + tid];
  __syncthreads();

  // self embedding gather (shared across the 3 edge types)
#pragma unroll
  for (int r = 0; r < RPB; ++r)
    xs[r][tid] = self_emb[iid[r] * DD + tid];

  float out_acc[RPB];
  if constexpr (DO_OUT) {
#pragma unroll
    for (int r = 0; r < RPB; ++r) out_acc[r] = 0.f;
  }

  for (int m = 0; m < 3; ++m) {
    const bool is_sess = (m == 2) && (nb2 == nullptr);
    float acc[RPB];

    if (is_sess) {
#pragma unroll
      for (int r = 0; r < RPB; ++r)
        acc[r] = session[(n0 + r) * DD + tid];
    } else {
      const int*   nb = (m == 0) ? nb0 : (m == 1) ? nb1 : nb2;
      const float* et = (m == 0) ? emb0 : (m == 1) ? emb1 : emb2;
      const float* W  = (m == 0) ? W0 : (m == 1) ? W1 : W2;
      const float* bb = (m == 0) ? b0 : (m == 1) ? b1 : b2;

      // neighbor gather + mean -> xs[r][128..255]
#pragma unroll
      for (int r = 0; r < RPB; ++r) {
        const int base = iid[r] * KK;
        float s = 0.f;
#pragma unroll
        for (int k = 0; k < KK; ++k)
          s += et[nb[base + k] * DD + tid];
        xs[r][DD + tid] = s * (1.f / KK);
      }
      __syncthreads();

      // matvec: h[d] = relu(b[d] + sum_j x[j] * W[j][d]), 256 j's, chunk 4
#pragma unroll
      for (int r = 0; r < RPB; ++r) acc[r] = bb[tid];
      for (int jj = 0; jj < (2 * DD) / 4; ++jj) {
        const float* Wc = W + jj * 4 * DD + tid;
        const float w0 = Wc[0], w1 = Wc[DD], w2 = Wc[2 * DD], w3 = Wc[3 * DD];
#pragma unroll
        for (int r = 0; r < RPB; ++r) {
          const float4 xv = *reinterpret_cast<const float4*>(&xs[r][jj * 4]);
          acc[r] = fmaf(xv.x, w0, acc[r]);
          acc[r] = fmaf(xv.y, w1, acc[r]);
          acc[r] = fmaf(xv.z, w2, acc[r]);
          acc[r] = fmaf(xv.w, w3, acc[r]);
        }
      }
#pragma unroll
      for (int r = 0; r < RPB; ++r) acc[r] = fmaxf(acc[r], 0.f);
    }

    if constexpr (STORE_H) {
#pragma unroll
      for (int r = 0; r < RPB; ++r)
        h_store[((size_t)(row_base + n0 + r) * 3 + m) * DD + tid] = acc[r];
    }
    if constexpr (DO_OUT) {
      const float bm = beta[m];
#pragma unroll
      for (int r = 0; r < RPB; ++r) out_acc[r] = fmaf(bm, acc[r], out_acc[r]);
    }
    if constexpr (DO_W) {
      // w[n,m] = sum_d tanh( (h @ Ws)[d] + bs[d] ) * q[d]
#pragma unroll
      for (int r = 0; r < RPB; ++r) hs[r][tid] = acc[r];
      __syncthreads();
      float acc2[RPB];
#pragma unroll
      for (int r = 0; r < RPB; ++r) acc2[r] = bs[tid];
      for (int jj = 0; jj < DD / 4; ++jj) {
        const float* Wc = Ws + jj * 4 * DD + tid;
        const float w0 = Wc[0], w1 = Wc[DD], w2 = Wc[2 * DD], w3 = Wc[3 * DD];
#pragma unroll
        for (int r = 0; r < RPB; ++r) {
          const float4 hv = *reinterpret_cast<const float4*>(&hs[r][jj * 4]);
          acc2[r] = fmaf(hv.x, w0, acc2[r]);
          acc2[r] = fmaf(hv.y, w1, acc2[r]);
          acc2[r] = fmaf(hv.z, w2, acc2[r]);
          acc2[r] = fmaf(hv.w, w3, acc2[r]);
        }
      }
      const float qv = q[tid];
#pragma unroll
      for (int r = 0; r < RPB; ++r) {
        float v = tanhf(acc2[r]) * qv;
        v = wave_reduce_sum(v);
        if ((tid & 63) == 0) red[tid >> 6][r] = v;
      }
      __syncthreads();
      if (tid == 0) {
        float c = 0.f;
#pragma unroll
        for (int w = 0; w < 2; ++w)
#pragma unroll
          for (int r = 0; r < RPB; ++r) c += red[w][r];
        atomicAdd(&wsum[(blockIdx.x & 63) * 4 + m], c);  // 64-way spread buckets
      }
    }
    __syncthreads();  // xs/hs/red reused next m
  }

  if constexpr (DO_OUT) {
#pragma unroll
    for (int r = 0; r < RPB; ++r)
      out[(n0 + r) * DD + tid] = out_acc[r];
  }
}

// beta[g][m] = softmax_m( mean_n w[n,m] )
__global__ void k_beta(const float* __restrict__ wsum, float* __restrict__ beta) {
  if (threadIdx.x == 0 && blockIdx.x == 0) {
    const float invN[3] = {1.f / 51200.f, 1.f / 1024.f, 1.f / 1024.f};
    for (int g = 0; g < 3; ++g) {
      float s0 = 0.f, s1 = 0.f, s2 = 0.f;
      for (int bkt = 0; bkt < 64; ++bkt) {
        s0 += wsum[g * 256 + bkt * 4 + 0];
        s1 += wsum[g * 256 + bkt * 4 + 1];
        s2 += wsum[g * 256 + bkt * 4 + 2];
      }
      s0 *= invN[g]; s1 *= invN[g]; s2 *= invN[g];
      const float mx = fmaxf(s0, fmaxf(s1, s2));
      const float e0 = expf(s0 - mx), e1 = expf(s1 - mx), e2 = expf(s2 - mx);
      const float inv = 1.f / (e0 + e1 + e2);
      beta[g * 4 + 0] = e0 * inv;
      beta[g * 4 + 1] = e1 * inv;
      beta[g * 4 + 2] = e2 * inv;
    }
  }
}

// out[row,d] = sum_m beta[g(row)][m] * h[row,m,d]   (store-H path)
__global__ void k_out(const float* __restrict__ h, const float* __restrict__ beta,
                      float* __restrict__ out) {
  const int idx = blockIdx.x * blockDim.x + threadIdx.x;  // 53248*128 total
  const int row = idx >> 7;
  const int g = (row < 51200) ? 0 : ((row < 52224) ? 1 : 2);
  const float* bt = beta + g * 4;
  const size_t base = (size_t)idx + (size_t)row * 2 * DD;  // (row*3)*128 + d
  out[idx] = bt[0] * h[base] + bt[1] * h[base + DD] + bt[2] * h[base + 2 * DD];
}

// ---------------------------------------------------------------------------

struct Ptrs {
  const int *item, *locs, *times;
  const float *session, *loc_emb, *time_emb, *item_emb;
  const int *nb_IL, *nb_TL, *nb_IT, *nb_LT, *nb_II, *nb_LI, *nb_TI;
  const float *W_IL, *b_IL, *W_TL, *b_TL, *W_IT, *b_IT, *W_LT, *b_LT;
  const float *W_II, *b_II, *W_LI, *b_LI, *W_TI, *b_TI;
  const float *Ws_l, *bs_l, *q_l, *Ws_t, *bs_t, *q_t, *Ws_i, *bs_i, *q_i;
  float *hbuf, *wsum, *betap;
  float *out_i, *out_l, *out_t;
};

template <bool SH, bool DW, bool DOo>
static void launch_all(const Ptrs& p, hipStream_t s) {
  const dim3 blk(128);
  // items: m = [II, TI, LI]
  k_group<SH, DW, DOo><<<dim3(51200 / RPB), blk, 0, s>>>(
      51200, 0, p.item, p.item_emb,
      p.nb_II, p.item_emb, p.W_II, p.b_II,
      p.nb_TI, p.time_emb, p.W_TI, p.b_TI,
      p.nb_LI, p.loc_emb,  p.W_LI, p.b_LI,
      (const float*)nullptr, p.Ws_i, p.bs_i, p.q_i,
      p.hbuf, p.wsum + 0, p.betap + 0, p.out_i);
  // locs: m = [IL, TL, session]
  k_group<SH, DW, DOo><<<dim3(1024 / RPB), blk, 0, s>>>(
      1024, 51200, p.locs, p.loc_emb,
      p.nb_IL, p.item_emb, p.W_IL, p.b_IL,
      p.nb_TL, p.time_emb, p.W_TL, p.b_TL,
      (const int*)nullptr, (const float*)nullptr, (const float*)nullptr, (const float*)nullptr,
      p.session, p.Ws_l, p.bs_l, p.q_l,
      p.hbuf, p.wsum + 256, p.betap + 4, p.out_l);
  // times: m = [IT, LT, session]
  k_group<SH, DW, DOo><<<dim3(1024 / RPB), blk, 0, s>>>(
      1024, 52224, p.times, p.time_emb,
      p.nb_IT, p.item_emb, p.W_IT, p.b_IT,
      p.nb_LT, p.loc_emb,  p.W_LT, p.b_LT,
      (const int*)nullptr, (const float*)nullptr, (const float*)nullptr, (const float*)nullptr,
      p.session, p.Ws_t, p.bs_t, p.q_t,
      p.hbuf, p.wsum + 512, p.betap + 8, p.out_t);
}

extern "C" void kernel_launch(void* const* d_in, const int* in_sizes, int n_in,
                              void* d_out, int out_size, void* d_ws, size_t ws_size,
                              hipStream_t stream) {
  Ptrs p;
  p.item     = (const int*)  d_in[0];
  p.locs     = (const int*)  d_in[1];
  p.times    = (const int*)  d_in[2];
  p.session  = (const float*)d_in[3];
  p.loc_emb  = (const float*)d_in[4];
  p.time_emb = (const float*)d_in[5];
  p.item_emb = (const float*)d_in[6];
  p.nb_IL = (const int*)d_in[7];
  p.nb_TL = (const int*)d_in[8];
  p.nb_IT = (const int*)d_in[9];
  p.nb_LT = (const int*)d_in[10];
  p.nb_II = (const int*)d_in[11];
  p.nb_LI = (const int*)d_in[12];
  p.nb_TI = (const int*)d_in[13];
  p.W_IL = (const float*)d_in[14]; p.b_IL = (const float*)d_in[15];
  p.W_TL = (const float*)d_in[16]; p.b_TL = (const float*)d_in[17];
  p.W_IT = (const float*)d_in[18]; p.b_IT = (const float*)d_in[19];
  p.W_LT = (const float*)d_in[20]; p.b_LT = (const float*)d_in[21];
  p.W_II = (const float*)d_in[22]; p.b_II = (const float*)d_in[23];
  p.W_LI = (const float*)d_in[24]; p.b_LI = (const float*)d_in[25];
  p.W_TI = (const float*)d_in[26]; p.b_TI = (const float*)d_in[27];
  p.Ws_l = (const float*)d_in[28]; p.bs_l = (const float*)d_in[29]; p.q_l = (const float*)d_in[30];
  p.Ws_t = (const float*)d_in[31]; p.bs_t = (const float*)d_in[32]; p.q_t = (const float*)d_in[33];
  p.Ws_i = (const float*)d_in[34]; p.bs_i = (const float*)d_in[35]; p.q_i = (const float*)d_in[36];

  float* outp = (float*)d_out;
  p.out_i = outp;
  p.out_l = outp + (size_t)51200 * DD;
  p.out_t = p.out_l + (size_t)1024 * DD;

  float* ws_f = (float*)d_ws;
  p.wsum  = ws_f;          // [3 groups][64 buckets][4]
  p.betap = ws_f + 1024;   // [3][4]
  p.hbuf  = ws_f + 4096;   // [53248 rows][3][128] f32

  const size_t needed = 4096ull * 4 + 53248ull * 3 * DD * 4;
  const bool storeH = ws_size >= needed;

  // zero w-accumulators (ws poisoned once; we accumulate every call)
  size_t zbytes = 16384;
  if (zbytes > ws_size) zbytes = ws_size;
  hipMemsetAsync(d_ws, 0, zbytes, stream);

  if (storeH) launch_all<true, true, false>(p, stream);
  else        launch_all<false, true, false>(p, stream);

  k_beta<<<dim3(1), dim3(64), 0, stream>>>(p.wsum, p.betap);

  if (storeH) {
    k_out<<<dim3((53248 * 128) / 256), dim3(256), 0, stream>>>(p.hbuf, p.betap, outp);
  } else {
    launch_all<false, false, true>(p, stream);
  }
}

// Round 2
// 648.023 us; speedup vs baseline: 4.9838x; 4.9838x over previous
//
#include <hip/hip_runtime.h>

#define DD 128
#define KK 20
#define TRR 16
#define RPB 4

__device__ __forceinline__ float4 f4fma(float s, float4 a, float4 b) {
  b.x = fmaf(s, a.x, b.x); b.y = fmaf(s, a.y, b.y);
  b.z = fmaf(s, a.z, b.z); b.w = fmaf(s, a.w, b.w);
  return b;
}

// ---------------------------------------------------------------------------
// k_agg: one edge-type. Block = 256 threads, 16 rows.
// Phase 1: gather self + mean(neighbors) into LDS x[16][256].
// Phase 2: register-tiled matvec (2 rows x 4 cols per thread), relu, store h.
// hdst is pre-offset by (row_base*3 + m)*128; row stride is 3*128.
// ---------------------------------------------------------------------------
__global__ __launch_bounds__(256, 4)
void k_agg(const int* __restrict__ self_idx, const float* __restrict__ self_emb,
           const int* __restrict__ nb, const float* __restrict__ emb,
           const float* __restrict__ W, const float* __restrict__ bias,
           float* __restrict__ hdst) {
  __shared__ int ids[TRR];
  __shared__ int nidx[TRR][KK];
  __shared__ __align__(16) float xs[TRR][2 * DD];

  const int tid = threadIdx.x;
  const int n0 = blockIdx.x * TRR;

  if (tid < TRR) ids[tid] = self_idx[n0 + tid];
  __syncthreads();

  const int gr = tid >> 4;         // gather row 0..15
  const int gc = (tid & 15) * 8;   // gather col base (8 cols/thread)

  // stage neighbor indices
  for (int t = tid; t < TRR * KK; t += 256) {
    const int rr = t / KK, kk = t - rr * KK;
    nidx[rr][kk] = nb[(size_t)ids[rr] * KK + kk];
  }
  // self half of x
  {
    const float4* sp = reinterpret_cast<const float4*>(self_emb + (size_t)ids[gr] * DD + gc);
    const float4 s0 = sp[0], s1 = sp[1];
    *reinterpret_cast<float4*>(&xs[gr][gc])     = s0;
    *reinterpret_cast<float4*>(&xs[gr][gc + 4]) = s1;
  }
  __syncthreads();

  // aggregate half of x: mean over 20 neighbors
  {
    float4 a0 = make_float4(0.f, 0.f, 0.f, 0.f);
    float4 a1 = make_float4(0.f, 0.f, 0.f, 0.f);
#pragma unroll 5
    for (int k = 0; k < KK; ++k) {
      const float4* rp = reinterpret_cast<const float4*>(emb + (size_t)nidx[gr][k] * DD + gc);
      const float4 v0 = rp[0], v1 = rp[1];
      a0.x += v0.x; a0.y += v0.y; a0.z += v0.z; a0.w += v0.w;
      a1.x += v1.x; a1.y += v1.y; a1.z += v1.z; a1.w += v1.w;
    }
    const float sc = 1.f / KK;
    a0.x *= sc; a0.y *= sc; a0.z *= sc; a0.w *= sc;
    a1.x *= sc; a1.y *= sc; a1.z *= sc; a1.w *= sc;
    *reinterpret_cast<float4*>(&xs[gr][DD + gc])     = a0;
    *reinterpret_cast<float4*>(&xs[gr][DD + gc + 4]) = a1;
  }
  __syncthreads();

  // matvec: thread = (ty: 2 rows, tx: 4 cols)
  const int tx = tid & 31, ty = tid >> 5;
  const int c0 = tx * 4;
  const int r0 = 2 * ty, r1 = r0 + 1;
  const float4 bv = *reinterpret_cast<const float4*>(bias + c0);
  float4 acc0 = bv, acc1 = bv;
  const float* Wp = W + c0;
#pragma unroll 2
  for (int j = 0; j < 2 * DD; j += 4) {
    const float4 w0 = *reinterpret_cast<const float4*>(Wp + (size_t)(j + 0) * DD);
    const float4 w1 = *reinterpret_cast<const float4*>(Wp + (size_t)(j + 1) * DD);
    const float4 w2 = *reinterpret_cast<const float4*>(Wp + (size_t)(j + 2) * DD);
    const float4 w3 = *reinterpret_cast<const float4*>(Wp + (size_t)(j + 3) * DD);
    const float4 xa = *reinterpret_cast<const float4*>(&xs[r0][j]);
    const float4 xb = *reinterpret_cast<const float4*>(&xs[r1][j]);
    acc0 = f4fma(xa.x, w0, acc0); acc0 = f4fma(xa.y, w1, acc0);
    acc0 = f4fma(xa.z, w2, acc0); acc0 = f4fma(xa.w, w3, acc0);
    acc1 = f4fma(xb.x, w0, acc1); acc1 = f4fma(xb.y, w1, acc1);
    acc1 = f4fma(xb.z, w2, acc1); acc1 = f4fma(xb.w, w3, acc1);
  }
  acc0.x = fmaxf(acc0.x, 0.f); acc0.y = fmaxf(acc0.y, 0.f);
  acc0.z = fmaxf(acc0.z, 0.f); acc0.w = fmaxf(acc0.w, 0.f);
  acc1.x = fmaxf(acc1.x, 0.f); acc1.y = fmaxf(acc1.y, 0.f);
  acc1.z = fmaxf(acc1.z, 0.f); acc1.w = fmaxf(acc1.w, 0.f);
  *reinterpret_cast<float4*>(hdst + (size_t)(n0 + r0) * 3 * DD + c0) = acc0;
  *reinterpret_cast<float4*>(hdst + (size_t)(n0 + r1) * 3 * DD + c0) = acc1;
}

// ---------------------------------------------------------------------------
// k_w: w[hrow] = tanh(h@Ws+bs)@q for 16 hrows/block; atomic into wsum buckets.
// ---------------------------------------------------------------------------
__global__ __launch_bounds__(256, 4)
void k_w(const float* __restrict__ hsrc, const float* __restrict__ Ws,
         const float* __restrict__ bsv, const float* __restrict__ q,
         float* __restrict__ wsum_g) {
  __shared__ __align__(16) float hs[TRR][DD];
  __shared__ float red[TRR];
  const int tid = threadIdx.x;
  const int h0 = blockIdx.x * TRR;
  {
    const int r = tid >> 4, c = (tid & 15) * 8;
    const float4* sp = reinterpret_cast<const float4*>(hsrc + (size_t)(h0 + r) * DD + c);
    *reinterpret_cast<float4*>(&hs[r][c])     = sp[0];
    *reinterpret_cast<float4*>(&hs[r][c + 4]) = sp[1];
  }
  __syncthreads();
  const int tx = tid & 31, ty = tid >> 5;
  const int c0 = tx * 4;
  const int r0 = 2 * ty, r1 = r0 + 1;
  const float4 bv = *reinterpret_cast<const float4*>(bsv + c0);
  float4 acc0 = bv, acc1 = bv;
  const float* Wp = Ws + c0;
#pragma unroll 2
  for (int j = 0; j < DD; j += 4) {
    const float4 w0 = *reinterpret_cast<const float4*>(Wp + (size_t)(j + 0) * DD);
    const float4 w1 = *reinterpret_cast<const float4*>(Wp + (size_t)(j + 1) * DD);
    const float4 w2 = *reinterpret_cast<const float4*>(Wp + (size_t)(j + 2) * DD);
    const float4 w3 = *reinterpret_cast<const float4*>(Wp + (size_t)(j + 3) * DD);
    const float4 xa = *reinterpret_cast<const float4*>(&hs[r0][j]);
    const float4 xb = *reinterpret_cast<const float4*>(&hs[r1][j]);
    acc0 = f4fma(xa.x, w0, acc0); acc0 = f4fma(xa.y, w1, acc0);
    acc0 = f4fma(xa.z, w2, acc0); acc0 = f4fma(xa.w, w3, acc0);
    acc1 = f4fma(xb.x, w0, acc1); acc1 = f4fma(xb.y, w1, acc1);
    acc1 = f4fma(xb.z, w2, acc1); acc1 = f4fma(xb.w, w3, acc1);
  }
  const float4 qv = *reinterpret_cast<const float4*>(q + c0);
  float v0 = tanhf(acc0.x) * qv.x + tanhf(acc0.y) * qv.y +
             tanhf(acc0.z) * qv.z + tanhf(acc0.w) * qv.w;
  float v1 = tanhf(acc1.x) * qv.x + tanhf(acc1.y) * qv.y +
             tanhf(acc1.z) * qv.z + tanhf(acc1.w) * qv.w;
#pragma unroll
  for (int off = 1; off < 32; off <<= 1) {
    v0 += __shfl_xor(v0, off, 64);
    v1 += __shfl_xor(v1, off, 64);
  }
  if (tx == 0) { red[r0] = v0; red[r1] = v1; }
  __syncthreads();
  if (tid < TRR) {
    const int m = (h0 + tid) % 3;
    atomicAdd(&wsum_g[(blockIdx.x & 63) * 4 + m], red[tid]);
  }
}

// session rows -> hbuf[(51200+n)*3+2] and [(52224+n)*3+2]
__global__ void k_sess(const float* __restrict__ session, float* __restrict__ hbuf) {
  const int t = blockIdx.x * blockDim.x + threadIdx.x;  // 65536 float4 slots
  const int row = t >> 5;          // 0..2047
  const int c0 = (t & 31) * 4;
  const int n = row & 1023;
  const size_t grow = (row < 1024) ? (size_t)(51200 + n) : (size_t)(52224 + n);
  const float4 v = *reinterpret_cast<const float4*>(session + (size_t)n * DD + c0);
  *reinterpret_cast<float4*>(hbuf + (grow * 3 + 2) * DD + c0) = v;
}

// beta[g][m] = softmax_m( mean_n w[n,m] )
__global__ void k_beta(const float* __restrict__ wsum, float* __restrict__ beta) {
  if (threadIdx.x == 0 && blockIdx.x == 0) {
    const float invN[3] = {1.f / 51200.f, 1.f / 1024.f, 1.f / 1024.f};
    for (int g = 0; g < 3; ++g) {
      float s0 = 0.f, s1 = 0.f, s2 = 0.f;
      for (int bkt = 0; bkt < 64; ++bkt) {
        s0 += wsum[g * 256 + bkt * 4 + 0];
        s1 += wsum[g * 256 + bkt * 4 + 1];
        s2 += wsum[g * 256 + bkt * 4 + 2];
      }
      s0 *= invN[g]; s1 *= invN[g]; s2 *= invN[g];
      const float mx = fmaxf(s0, fmaxf(s1, s2));
      const float e0 = expf(s0 - mx), e1 = expf(s1 - mx), e2 = expf(s2 - mx);
      const float inv = 1.f / (e0 + e1 + e2);
      beta[g * 4 + 0] = e0 * inv;
      beta[g * 4 + 1] = e1 * inv;
      beta[g * 4 + 2] = e2 * inv;
    }
  }
}

// out[row,d] = sum_m beta[g(row)][m] * h[row,m,d]
__global__ void k_out(const float* __restrict__ h, const float* __restrict__ beta,
                      float* __restrict__ out) {
  const int idx = blockIdx.x * blockDim.x + threadIdx.x;
  const int row = idx >> 7;
  const int g = (row < 51200) ? 0 : ((row < 52224) ? 1 : 2);
  const float* bt = beta + g * 4;
  const size_t base = (size_t)idx + (size_t)row * 2 * DD;
  out[idx] = bt[0] * h[base] + bt[1] * h[base + DD] + bt[2] * h[base + 2 * DD];
}

// ---------------------------------------------------------------------------
// Fallback fused kernel (ws too small for hbuf) — round-1 code, known-correct.
// ---------------------------------------------------------------------------
__device__ __forceinline__ float wave_reduce_sum(float v) {
#pragma unroll
  for (int off = 32; off > 0; off >>= 1) v += __shfl_down(v, off, 64);
  return v;
}

template <bool STORE_H, bool DO_W, bool DO_OUT>
__global__ __launch_bounds__(128)
void k_group(int N, int row_base,
             const int* __restrict__ self_idx, const float* __restrict__ self_emb,
             const int* __restrict__ nb0, const float* __restrict__ emb0,
             const float* __restrict__ W0, const float* __restrict__ b0,
             const int* __restrict__ nb1, const float* __restrict__ emb1,
             const float* __restrict__ W1, const float* __restrict__ b1,
             const int* __restrict__ nb2, const float* __restrict__ emb2,
             const float* __restrict__ W2, const float* __restrict__ b2,
             const float* __restrict__ session,
             const float* __restrict__ Ws, const float* __restrict__ bs,
             const float* __restrict__ q,
             float* __restrict__ h_store, float* __restrict__ wsum,
             const float* __restrict__ beta, float* __restrict__ out) {
  __shared__ __align__(16) float xs[RPB][2 * DD];
  __shared__ __align__(16) float hs[RPB][DD];
  __shared__ float red[2][RPB];
  __shared__ int iid[RPB];
  const int tid = threadIdx.x;
  const int n0 = blockIdx.x * RPB;
  if (tid < RPB) iid[tid] = self_idx[n0 + tid];
  __syncthreads();
#pragma unroll
  for (int r = 0; r < RPB; ++r) xs[r][tid] = self_emb[iid[r] * DD + tid];
  float out_acc[RPB];
  if constexpr (DO_OUT) {
#pragma unroll
    for (int r = 0; r < RPB; ++r) out_acc[r] = 0.f;
  }
  for (int m = 0; m < 3; ++m) {
    const bool is_sess = (m == 2) && (nb2 == nullptr);
    float acc[RPB];
    if (is_sess) {
#pragma unroll
      for (int r = 0; r < RPB; ++r) acc[r] = session[(n0 + r) * DD + tid];
    } else {
      const int*   nbp = (m == 0) ? nb0 : (m == 1) ? nb1 : nb2;
      const float* et  = (m == 0) ? emb0 : (m == 1) ? emb1 : emb2;
      const float* W   = (m == 0) ? W0 : (m == 1) ? W1 : W2;
      const float* bb  = (m == 0) ? b0 : (m == 1) ? b1 : b2;
#pragma unroll
      for (int r = 0; r < RPB; ++r) {
        const int base = iid[r] * KK;
        float s = 0.f;
#pragma unroll 5
        for (int k = 0; k < KK; ++k) s += et[nbp[base + k] * DD + tid];
        xs[r][DD + tid] = s * (1.f / KK);
      }
      __syncthreads();
#pragma unroll
      for (int r = 0; r < RPB; ++r) acc[r] = bb[tid];
      for (int jj = 0; jj < (2 * DD) / 4; ++jj) {
        const float* Wc = W + jj * 4 * DD + tid;
        const float w0 = Wc[0], w1 = Wc[DD], w2 = Wc[2 * DD], w3 = Wc[3 * DD];
#pragma unroll
        for (int r = 0; r < RPB; ++r) {
          const float4 xv = *reinterpret_cast<const float4*>(&xs[r][jj * 4]);
          acc[r] = fmaf(xv.x, w0, acc[r]); acc[r] = fmaf(xv.y, w1, acc[r]);
          acc[r] = fmaf(xv.z, w2, acc[r]); acc[r] = fmaf(xv.w, w3, acc[r]);
        }
      }
#pragma unroll
      for (int r = 0; r < RPB; ++r) acc[r] = fmaxf(acc[r], 0.f);
    }
    if constexpr (STORE_H) {
#pragma unroll
      for (int r = 0; r < RPB; ++r)
        h_store[((size_t)(row_base + n0 + r) * 3 + m) * DD + tid] = acc[r];
    }
    if constexpr (DO_OUT) {
      const float bm = beta[m];
#pragma unroll
      for (int r = 0; r < RPB; ++r) out_acc[r] = fmaf(bm, acc[r], out_acc[r]);
    }
    if constexpr (DO_W) {
#pragma unroll
      for (int r = 0; r < RPB; ++r) hs[r][tid] = acc[r];
      __syncthreads();
      float acc2[RPB];
#pragma unroll
      for (int r = 0; r < RPB; ++r) acc2[r] = bs[tid];
      for (int jj = 0; jj < DD / 4; ++jj) {
        const float* Wc = Ws + jj * 4 * DD + tid;
        const float w0 = Wc[0], w1 = Wc[DD], w2 = Wc[2 * DD], w3 = Wc[3 * DD];
#pragma unroll
        for (int r = 0; r < RPB; ++r) {
          const float4 hv = *reinterpret_cast<const float4*>(&hs[r][jj * 4]);
          acc2[r] = fmaf(hv.x, w0, acc2[r]); acc2[r] = fmaf(hv.y, w1, acc2[r]);
          acc2[r] = fmaf(hv.z, w2, acc2[r]); acc2[r] = fmaf(hv.w, w3, acc2[r]);
        }
      }
      const float qv = q[tid];
#pragma unroll
      for (int r = 0; r < RPB; ++r) {
        float v = tanhf(acc2[r]) * qv;
        v = wave_reduce_sum(v);
        if ((tid & 63) == 0) red[tid >> 6][r] = v;
      }
      __syncthreads();
      if (tid == 0) {
        float c = 0.f;
#pragma unroll
        for (int w = 0; w < 2; ++w)
#pragma unroll
          for (int r = 0; r < RPB; ++r) c += red[w][r];
        atomicAdd(&wsum[(blockIdx.x & 63) * 4 + m], c);
      }
    }
    __syncthreads();
  }
  if constexpr (DO_OUT) {
#pragma unroll
    for (int r = 0; r < RPB; ++r) out[(n0 + r) * DD + tid] = out_acc[r];
  }
}

// ---------------------------------------------------------------------------

struct Ptrs {
  const int *item, *locs, *times;
  const float *session, *loc_emb, *time_emb, *item_emb;
  const int *nb_IL, *nb_TL, *nb_IT, *nb_LT, *nb_II, *nb_LI, *nb_TI;
  const float *W_IL, *b_IL, *W_TL, *b_TL, *W_IT, *b_IT, *W_LT, *b_LT;
  const float *W_II, *b_II, *W_LI, *b_LI, *W_TI, *b_TI;
  const float *Ws_l, *bs_l, *q_l, *Ws_t, *bs_t, *q_t, *Ws_i, *bs_i, *q_i;
  float *hbuf, *wsum, *betap;
  float *out_i, *out_l, *out_t;
};

template <bool SH, bool DW, bool DOo>
static void launch_all(const Ptrs& p, hipStream_t s) {
  const dim3 blk(128);
  k_group<SH, DW, DOo><<<dim3(51200 / RPB), blk, 0, s>>>(
      51200, 0, p.item, p.item_emb,
      p.nb_II, p.item_emb, p.W_II, p.b_II,
      p.nb_TI, p.time_emb, p.W_TI, p.b_TI,
      p.nb_LI, p.loc_emb,  p.W_LI, p.b_LI,
      (const float*)nullptr, p.Ws_i, p.bs_i, p.q_i,
      p.hbuf, p.wsum + 0, p.betap + 0, p.out_i);
  k_group<SH, DW, DOo><<<dim3(1024 / RPB), blk, 0, s>>>(
      1024, 51200, p.locs, p.loc_emb,
      p.nb_IL, p.item_emb, p.W_IL, p.b_IL,
      p.nb_TL, p.time_emb, p.W_TL, p.b_TL,
      (const int*)nullptr, (const float*)nullptr, (const float*)nullptr, (const float*)nullptr,
      p.session, p.Ws_l, p.bs_l, p.q_l,
      p.hbuf, p.wsum + 256, p.betap + 4, p.out_l);
  k_group<SH, DW, DOo><<<dim3(1024 / RPB), blk, 0, s>>>(
      1024, 52224, p.times, p.time_emb,
      p.nb_IT, p.item_emb, p.W_IT, p.b_IT,
      p.nb_LT, p.loc_emb,  p.W_LT, p.b_LT,
      (const int*)nullptr, (const float*)nullptr, (const float*)nullptr, (const float*)nullptr,
      p.session, p.Ws_t, p.bs_t, p.q_t,
      p.hbuf, p.wsum + 512, p.betap + 8, p.out_t);
}

extern "C" void kernel_launch(void* const* d_in, const int* in_sizes, int n_in,
                              void* d_out, int out_size, void* d_ws, size_t ws_size,
                              hipStream_t stream) {
  Ptrs p;
  p.item     = (const int*)  d_in[0];
  p.locs     = (const int*)  d_in[1];
  p.times    = (const int*)  d_in[2];
  p.session  = (const float*)d_in[3];
  p.loc_emb  = (const float*)d_in[4];
  p.time_emb = (const float*)d_in[5];
  p.item_emb = (const float*)d_in[6];
  p.nb_IL = (const int*)d_in[7];
  p.nb_TL = (const int*)d_in[8];
  p.nb_IT = (const int*)d_in[9];
  p.nb_LT = (const int*)d_in[10];
  p.nb_II = (const int*)d_in[11];
  p.nb_LI = (const int*)d_in[12];
  p.nb_TI = (const int*)d_in[13];
  p.W_IL = (const float*)d_in[14]; p.b_IL = (const float*)d_in[15];
  p.W_TL = (const float*)d_in[16]; p.b_TL = (const float*)d_in[17];
  p.W_IT = (const float*)d_in[18]; p.b_IT = (const float*)d_in[19];
  p.W_LT = (const float*)d_in[20]; p.b_LT = (const float*)d_in[21];
  p.W_II = (const float*)d_in[22]; p.b_II = (const float*)d_in[23];
  p.W_LI = (const float*)d_in[24]; p.b_LI = (const float*)d_in[25];
  p.W_TI = (const float*)d_in[26]; p.b_TI = (const float*)d_in[27];
  p.Ws_l = (const float*)d_in[28]; p.bs_l = (const float*)d_in[29]; p.q_l = (const float*)d_in[30];
  p.Ws_t = (const float*)d_in[31]; p.bs_t = (const float*)d_in[32]; p.q_t = (const float*)d_in[33];
  p.Ws_i = (const float*)d_in[34]; p.bs_i = (const float*)d_in[35]; p.q_i = (const float*)d_in[36];

  float* outp = (float*)d_out;
  p.out_i = outp;
  p.out_l = outp + (size_t)51200 * DD;
  p.out_t = p.out_l + (size_t)1024 * DD;

  float* ws_f = (float*)d_ws;
  p.wsum  = ws_f;          // [3][64][4]
  p.betap = ws_f + 1024;   // [3][4]
  p.hbuf  = ws_f + 4096;   // [53248][3][128] f32

  const size_t needed = 4096ull * 4 + 53248ull * 3 * DD * 4;
  const bool storeH = ws_size >= needed;

  size_t zbytes = 16384;
  if (zbytes > ws_size) zbytes = ws_size;
  hipMemsetAsync(d_ws, 0, zbytes, stream);

  if (storeH) {
    // session rows into hbuf
    k_sess<<<dim3(256), dim3(256), 0, stream>>>(p.session, p.hbuf);
    // 7 edge-type aggregations
    const dim3 blk(256);
    const int gi = 51200 / TRR, gs = 1024 / TRR;
    k_agg<<<dim3(gi), blk, 0, stream>>>(p.item, p.item_emb, p.nb_II, p.item_emb,
                                        p.W_II, p.b_II, p.hbuf + 0 * DD);
    k_agg<<<dim3(gi), blk, 0, stream>>>(p.item, p.item_emb, p.nb_TI, p.time_emb,
                                        p.W_TI, p.b_TI, p.hbuf + 1 * DD);
    k_agg<<<dim3(gi), blk, 0, stream>>>(p.item, p.item_emb, p.nb_LI, p.loc_emb,
                                        p.W_LI, p.b_LI, p.hbuf + 2 * DD);
    k_agg<<<dim3(gs), blk, 0, stream>>>(p.locs, p.loc_emb, p.nb_IL, p.item_emb,
                                        p.W_IL, p.b_IL, p.hbuf + ((size_t)51200 * 3 + 0) * DD);
    k_agg<<<dim3(gs), blk, 0, stream>>>(p.locs, p.loc_emb, p.nb_TL, p.time_emb,
                                        p.W_TL, p.b_TL, p.hbuf + ((size_t)51200 * 3 + 1) * DD);
    k_agg<<<dim3(gs), blk, 0, stream>>>(p.times, p.time_emb, p.nb_IT, p.item_emb,
                                        p.W_IT, p.b_IT, p.hbuf + ((size_t)52224 * 3 + 0) * DD);
    k_agg<<<dim3(gs), blk, 0, stream>>>(p.times, p.time_emb, p.nb_LT, p.loc_emb,
                                        p.W_LT, p.b_LT, p.hbuf + ((size_t)52224 * 3 + 1) * DD);
    // semantic-attention scores
    k_w<<<dim3(153600 / TRR), blk, 0, stream>>>(p.hbuf, p.Ws_i, p.bs_i, p.q_i, p.wsum + 0);
    k_w<<<dim3(3072 / TRR),   blk, 0, stream>>>(p.hbuf + (size_t)51200 * 3 * DD,
                                                p.Ws_l, p.bs_l, p.q_l, p.wsum + 256);
    k_w<<<dim3(3072 / TRR),   blk, 0, stream>>>(p.hbuf + (size_t)52224 * 3 * DD,
                                                p.Ws_t, p.bs_t, p.q_t, p.wsum + 512);
    k_beta<<<dim3(1), dim3(64), 0, stream>>>(p.wsum, p.betap);
    k_out<<<dim3((53248 * 128) / 256), dim3(256), 0, stream>>>(p.hbuf, p.betap, outp);
  } else {
    launch_all<false, true, false>(p, stream);
    k_beta<<<dim3(1), dim3(64), 0, stream>>>(p.wsum, p.betap);
    launch_all<false, false, true>(p, stream);
  }
}

// Round 3
// 619.353 us; speedup vs baseline: 5.2145x; 1.0463x over previous
//
#include <hip/hip_runtime.h>

#define DD 128
#define KK 20
#define TRR 16

typedef unsigned int uint_t;
typedef unsigned short ushort_t;

__device__ __forceinline__ float4 f4fma(float s, float4 a, float4 b) {
  b.x = fmaf(s, a.x, b.x); b.y = fmaf(s, a.y, b.y);
  b.z = fmaf(s, a.z, b.z); b.w = fmaf(s, a.w, b.w);
  return b;
}

__device__ __forceinline__ float fast_tanh(float x) {
  // tanh(x) = 1 - 2/(e^{2x}+1); saturates to +-1 at inf, no branches
  const float e = __expf(2.f * x);
  return 1.f - 2.f / (e + 1.f);
}

__device__ __forceinline__ uint_t f2bf(float f) {
  const uint_t u = __float_as_uint(f);
  return (u + 0x7fffu + ((u >> 16) & 1u)) >> 16;  // RNE
}
__device__ __forceinline__ float bf_lo(uint_t u) { return __uint_as_float(u << 16); }
__device__ __forceinline__ float bf_hi(uint_t u) { return __uint_as_float(u & 0xffff0000u); }

// f32 table -> bf16 table, 8 elements/thread
__global__ __launch_bounds__(256)
void k_cvt(const float* __restrict__ in, ushort_t* __restrict__ out, int n8) {
  const int t = blockIdx.x * blockDim.x + threadIdx.x;
  if (t >= n8) return;
  const float4* ip = reinterpret_cast<const float4*>(in + (size_t)t * 8);
  const float4 a = ip[0], b = ip[1];
  uint4 o;
  o.x = f2bf(a.x) | (f2bf(a.y) << 16);
  o.y = f2bf(a.z) | (f2bf(a.w) << 16);
  o.z = f2bf(b.x) | (f2bf(b.y) << 16);
  o.w = f2bf(b.z) | (f2bf(b.w) << 16);
  reinterpret_cast<uint4*>(out)[t] = o;
}

// ---------------------------------------------------------------------------
// k_agg2: one edge-type, fused attention score.
// Phase 1: gather self + mean(neighbors) (bf16 tables if MODE=1) into xs[16][256]
// Phase 2: matvec 2 rows x 4 cols/thread, relu -> h; store to hbuf + LDS
// Phase 3: w = tanh(h@Ws+bs)@q per row; block-sum; one atomicAdd into bucket m
// ---------------------------------------------------------------------------
template <int MODE>
__global__ __launch_bounds__(256, 4)
void k_agg2(const int* __restrict__ self_idx,
            const ushort_t* __restrict__ self_b, const float* __restrict__ self_f,
            const int* __restrict__ nb,
            const ushort_t* __restrict__ emb_b, const float* __restrict__ emb_f,
            const float* __restrict__ W, const float* __restrict__ bias,
            const float* __restrict__ Ws, const float* __restrict__ bs,
            const float* __restrict__ q,
            float* __restrict__ hdst, float* __restrict__ wsum_g, int m) {
  __shared__ int ids[TRR];
  __shared__ int nidx[TRR][KK];
  __shared__ __align__(16) float xs[TRR][2 * DD];
  __shared__ float red[TRR];

  const int tid = threadIdx.x;
  const int n0 = blockIdx.x * TRR;

  if (tid < TRR) ids[tid] = self_idx[n0 + tid];
  __syncthreads();

  const int gr = tid >> 4;         // gather row 0..15
  const int gc = (tid & 15) * 8;   // 8 cols per thread

  for (int t = tid; t < TRR * KK; t += 256) {
    const int rr = t / KK, kk = t - rr * KK;
    nidx[rr][kk] = nb[(size_t)ids[rr] * KK + kk];
  }

  // self half
  if constexpr (MODE == 1) {
    const uint4 u = *reinterpret_cast<const uint4*>(self_b + ((size_t)ids[gr] << 7) + gc);
    xs[gr][gc + 0] = bf_lo(u.x); xs[gr][gc + 1] = bf_hi(u.x);
    xs[gr][gc + 2] = bf_lo(u.y); xs[gr][gc + 3] = bf_hi(u.y);
    xs[gr][gc + 4] = bf_lo(u.z); xs[gr][gc + 5] = bf_hi(u.z);
    xs[gr][gc + 6] = bf_lo(u.w); xs[gr][gc + 7] = bf_hi(u.w);
  } else {
    const float4* sp = reinterpret_cast<const float4*>(self_f + ((size_t)ids[gr] << 7) + gc);
    *reinterpret_cast<float4*>(&xs[gr][gc])     = sp[0];
    *reinterpret_cast<float4*>(&xs[gr][gc + 4]) = sp[1];
  }
  __syncthreads();

  // neighbor mean
  {
    float a[8];
#pragma unroll
    for (int i = 0; i < 8; ++i) a[i] = 0.f;
    if constexpr (MODE == 1) {
#pragma unroll 5
      for (int k = 0; k < KK; ++k) {
        const uint4 u = *reinterpret_cast<const uint4*>(emb_b + ((size_t)nidx[gr][k] << 7) + gc);
        a[0] += bf_lo(u.x); a[1] += bf_hi(u.x);
        a[2] += bf_lo(u.y); a[3] += bf_hi(u.y);
        a[4] += bf_lo(u.z); a[5] += bf_hi(u.z);
        a[6] += bf_lo(u.w); a[7] += bf_hi(u.w);
      }
    } else {
#pragma unroll 5
      for (int k = 0; k < KK; ++k) {
        const float4* rp = reinterpret_cast<const float4*>(emb_f + ((size_t)nidx[gr][k] << 7) + gc);
        const float4 v0 = rp[0], v1 = rp[1];
        a[0] += v0.x; a[1] += v0.y; a[2] += v0.z; a[3] += v0.w;
        a[4] += v1.x; a[5] += v1.y; a[6] += v1.z; a[7] += v1.w;
      }
    }
    const float sc = 1.f / KK;
#pragma unroll
    for (int i = 0; i < 8; ++i) xs[gr][DD + gc + i] = a[i] * sc;
  }
  __syncthreads();

  // matvec h = relu(x @ W + b)
  const int tx = tid & 31, ty = tid >> 5;
  const int c0 = tx * 4;
  const int r0 = 2 * ty, r1 = r0 + 1;
  float4 acc0, acc1;
  {
    const float4 bv = *reinterpret_cast<const float4*>(bias + c0);
    acc0 = bv; acc1 = bv;
    const float* Wp = W + c0;
#pragma unroll 2
    for (int j = 0; j < 2 * DD; j += 4) {
      const float4 w0 = *reinterpret_cast<const float4*>(Wp + (size_t)(j + 0) * DD);
      const float4 w1 = *reinterpret_cast<const float4*>(Wp + (size_t)(j + 1) * DD);
      const float4 w2 = *reinterpret_cast<const float4*>(Wp + (size_t)(j + 2) * DD);
      const float4 w3 = *reinterpret_cast<const float4*>(Wp + (size_t)(j + 3) * DD);
      const float4 xa = *reinterpret_cast<const float4*>(&xs[r0][j]);
      const float4 xb = *reinterpret_cast<const float4*>(&xs[r1][j]);
      acc0 = f4fma(xa.x, w0, acc0); acc0 = f4fma(xa.y, w1, acc0);
      acc0 = f4fma(xa.z, w2, acc0); acc0 = f4fma(xa.w, w3, acc0);
      acc1 = f4fma(xb.x, w0, acc1); acc1 = f4fma(xb.y, w1, acc1);
      acc1 = f4fma(xb.z, w2, acc1); acc1 = f4fma(xb.w, w3, acc1);
    }
    acc0.x = fmaxf(acc0.x, 0.f); acc0.y = fmaxf(acc0.y, 0.f);
    acc0.z = fmaxf(acc0.z, 0.f); acc0.w = fmaxf(acc0.w, 0.f);
    acc1.x = fmaxf(acc1.x, 0.f); acc1.y = fmaxf(acc1.y, 0.f);
    acc1.z = fmaxf(acc1.z, 0.f); acc1.w = fmaxf(acc1.w, 0.f);
    *reinterpret_cast<float4*>(hdst + (size_t)(n0 + r0) * 3 * DD + c0) = acc0;
    *reinterpret_cast<float4*>(hdst + (size_t)(n0 + r1) * 3 * DD + c0) = acc1;
  }

  // phase 3: w scores. reuse xs LDS as hs[16][128]
  float* hs = &xs[0][0];
  __syncthreads();  // everyone done reading xs
  *reinterpret_cast<float4*>(hs + r0 * DD + c0) = acc0;
  *reinterpret_cast<float4*>(hs + r1 * DD + c0) = acc1;
  __syncthreads();
  {
    const float4 bv = *reinterpret_cast<const float4*>(bs + c0);
    float4 s0 = bv, s1 = bv;
    const float* Wp = Ws + c0;
#pragma unroll 2
    for (int j = 0; j < DD; j += 4) {
      const float4 w0 = *reinterpret_cast<const float4*>(Wp + (size_t)(j + 0) * DD);
      const float4 w1 = *reinterpret_cast<const float4*>(Wp + (size_t)(j + 1) * DD);
      const float4 w2 = *reinterpret_cast<const float4*>(Wp + (size_t)(j + 2) * DD);
      const float4 w3 = *reinterpret_cast<const float4*>(Wp + (size_t)(j + 3) * DD);
      const float4 xa = *reinterpret_cast<const float4*>(hs + r0 * DD + j);
      const float4 xb = *reinterpret_cast<const float4*>(hs + r1 * DD + j);
      s0 = f4fma(xa.x, w0, s0); s0 = f4fma(xa.y, w1, s0);
      s0 = f4fma(xa.z, w2, s0); s0 = f4fma(xa.w, w3, s0);
      s1 = f4fma(xb.x, w0, s1); s1 = f4fma(xb.y, w1, s1);
      s1 = f4fma(xb.z, w2, s1); s1 = f4fma(xb.w, w3, s1);
    }
    const float4 qv = *reinterpret_cast<const float4*>(q + c0);
    float v0 = fast_tanh(s0.x) * qv.x + fast_tanh(s0.y) * qv.y +
               fast_tanh(s0.z) * qv.z + fast_tanh(s0.w) * qv.w;
    float v1 = fast_tanh(s1.x) * qv.x + fast_tanh(s1.y) * qv.y +
               fast_tanh(s1.z) * qv.z + fast_tanh(s1.w) * qv.w;
#pragma unroll
    for (int off = 1; off < 32; off <<= 1) {
      v0 += __shfl_xor(v0, off, 64);
      v1 += __shfl_xor(v1, off, 64);
    }
    if (tx == 0) { red[r0] = v0; red[r1] = v1; }
    __syncthreads();
    if (tid == 0) {
      float c = 0.f;
#pragma unroll
      for (int r = 0; r < TRR; ++r) c += red[r];
      atomicAdd(&wsum_g[(blockIdx.x & 63) * 4 + m], c);
    }
  }
}

// w scores for session rows (f32 src, contiguous [1024][128]); m=2 bucket
__global__ __launch_bounds__(256, 4)
void k_wsess(const float* __restrict__ hsrc, const float* __restrict__ Ws,
             const float* __restrict__ bsv, const float* __restrict__ q,
             float* __restrict__ wsum_g) {
  __shared__ __align__(16) float hs[TRR][DD];
  __shared__ float red[TRR];
  const int tid = threadIdx.x;
  const int h0 = blockIdx.x * TRR;
  {
    const int r = tid >> 4, c = (tid & 15) * 8;
    const float4* sp = reinterpret_cast<const float4*>(hsrc + (size_t)(h0 + r) * DD + c);
    *reinterpret_cast<float4*>(&hs[r][c])     = sp[0];
    *reinterpret_cast<float4*>(&hs[r][c + 4]) = sp[1];
  }
  __syncthreads();
  const int tx = tid & 31, ty = tid >> 5;
  const int c0 = tx * 4;
  const int r0 = 2 * ty, r1 = r0 + 1;
  const float4 bv = *reinterpret_cast<const float4*>(bsv + c0);
  float4 s0 = bv, s1 = bv;
  const float* Wp = Ws + c0;
#pragma unroll 2
  for (int j = 0; j < DD; j += 4) {
    const float4 w0 = *reinterpret_cast<const float4*>(Wp + (size_t)(j + 0) * DD);
    const float4 w1 = *reinterpret_cast<const float4*>(Wp + (size_t)(j + 1) * DD);
    const float4 w2 = *reinterpret_cast<const float4*>(Wp + (size_t)(j + 2) * DD);
    const float4 w3 = *reinterpret_cast<const float4*>(Wp + (size_t)(j + 3) * DD);
    const float4 xa = *reinterpret_cast<const float4*>(&hs[r0][j]);
    const float4 xb = *reinterpret_cast<const float4*>(&hs[r1][j]);
    s0 = f4fma(xa.x, w0, s0); s0 = f4fma(xa.y, w1, s0);
    s0 = f4fma(xa.z, w2, s0); s0 = f4fma(xa.w, w3, s0);
    s1 = f4fma(xb.x, w0, s1); s1 = f4fma(xb.y, w1, s1);
    s1 = f4fma(xb.z, w2, s1); s1 = f4fma(xb.w, w3, s1);
  }
  const float4 qv = *reinterpret_cast<const float4*>(q + c0);
  float v0 = fast_tanh(s0.x) * qv.x + fast_tanh(s0.y) * qv.y +
             fast_tanh(s0.z) * qv.z + fast_tanh(s0.w) * qv.w;
  float v1 = fast_tanh(s1.x) * qv.x + fast_tanh(s1.y) * qv.y +
             fast_tanh(s1.z) * qv.z + fast_tanh(s1.w) * qv.w;
#pragma unroll
  for (int off = 1; off < 32; off <<= 1) {
    v0 += __shfl_xor(v0, off, 64);
    v1 += __shfl_xor(v1, off, 64);
  }
  if (tx == 0) { red[r0] = v0; red[r1] = v1; }
  __syncthreads();
  if (tid == 0) {
    float c = 0.f;
#pragma unroll
    for (int r = 0; r < TRR; ++r) c += red[r];
    atomicAdd(&wsum_g[(blockIdx.x & 63) * 4 + 2], c);
  }
}

// session rows -> hbuf[(51200+n)*3+2] and [(52224+n)*3+2]
__global__ void k_sess(const float* __restrict__ session, float* __restrict__ hbuf) {
  const int t = blockIdx.x * blockDim.x + threadIdx.x;
  const int row = t >> 5;
  const int c0 = (t & 31) * 4;
  const int n = row & 1023;
  const size_t grow = (row < 1024) ? (size_t)(51200 + n) : (size_t)(52224 + n);
  const float4 v = *reinterpret_cast<const float4*>(session + (size_t)n * DD + c0);
  *reinterpret_cast<float4*>(hbuf + (grow * 3 + 2) * DD + c0) = v;
}

__global__ void k_beta(const float* __restrict__ wsum, float* __restrict__ beta) {
  if (threadIdx.x == 0 && blockIdx.x == 0) {
    const float invN[3] = {1.f / 51200.f, 1.f / 1024.f, 1.f / 1024.f};
    for (int g = 0; g < 3; ++g) {
      float s0 = 0.f, s1 = 0.f, s2 = 0.f;
      for (int bkt = 0; bkt < 64; ++bkt) {
        s0 += wsum[g * 256 + bkt * 4 + 0];
        s1 += wsum[g * 256 + bkt * 4 + 1];
        s2 += wsum[g * 256 + bkt * 4 + 2];
      }
      s0 *= invN[g]; s1 *= invN[g]; s2 *= invN[g];
      const float mx = fmaxf(s0, fmaxf(s1, s2));
      const float e0 = expf(s0 - mx), e1 = expf(s1 - mx), e2 = expf(s2 - mx);
      const float inv = 1.f / (e0 + e1 + e2);
      beta[g * 4 + 0] = e0 * inv;
      beta[g * 4 + 1] = e1 * inv;
      beta[g * 4 + 2] = e2 * inv;
    }
  }
}

__global__ void k_out(const float* __restrict__ h, const float* __restrict__ beta,
                      float* __restrict__ out) {
  const int idx = blockIdx.x * blockDim.x + threadIdx.x;
  const int row = idx >> 7;
  const int g = (row < 51200) ? 0 : ((row < 52224) ? 1 : 2);
  const float* bt = beta + g * 4;
  const size_t base = (size_t)idx + (size_t)row * 2 * DD;
  out[idx] = bt[0] * h[base] + bt[1] * h[base + DD] + bt[2] * h[base + 2 * DD];
}

// ---------------------------------------------------------------------------

extern "C" void kernel_launch(void* const* d_in, const int* in_sizes, int n_in,
                              void* d_out, int out_size, void* d_ws, size_t ws_size,
                              hipStream_t stream) {
  const int*   item     = (const int*)  d_in[0];
  const int*   locs     = (const int*)  d_in[1];
  const int*   times    = (const int*)  d_in[2];
  const float* session  = (const float*)d_in[3];
  const float* loc_emb  = (const float*)d_in[4];
  const float* time_emb = (const float*)d_in[5];
  const float* item_emb = (const float*)d_in[6];
  const int* nb_IL = (const int*)d_in[7];
  const int* nb_TL = (const int*)d_in[8];
  const int* nb_IT = (const int*)d_in[9];
  const int* nb_LT = (const int*)d_in[10];
  const int* nb_II = (const int*)d_in[11];
  const int* nb_LI = (const int*)d_in[12];
  const int* nb_TI = (const int*)d_in[13];
  const float* W_IL = (const float*)d_in[14]; const float* b_IL = (const float*)d_in[15];
  const float* W_TL = (const float*)d_in[16]; const float* b_TL = (const float*)d_in[17];
  const float* W_IT = (const float*)d_in[18]; const float* b_IT = (const float*)d_in[19];
  const float* W_LT = (const float*)d_in[20]; const float* b_LT = (const float*)d_in[21];
  const float* W_II = (const float*)d_in[22]; const float* b_II = (const float*)d_in[23];
  const float* W_LI = (const float*)d_in[24]; const float* b_LI = (const float*)d_in[25];
  const float* W_TI = (const float*)d_in[26]; const float* b_TI = (const float*)d_in[27];
  const float* Ws_l = (const float*)d_in[28]; const float* bs_l = (const float*)d_in[29];
  const float* q_l  = (const float*)d_in[30];
  const float* Ws_t = (const float*)d_in[31]; const float* bs_t = (const float*)d_in[32];
  const float* q_t  = (const float*)d_in[33];
  const float* Ws_i = (const float*)d_in[34]; const float* bs_i = (const float*)d_in[35];
  const float* q_i  = (const float*)d_in[36];

  float* outp = (float*)d_out;

  float* ws_f  = (float*)d_ws;
  float* wsum  = ws_f;          // [3 groups][64 buckets][4]
  float* betap = ws_f + 1024;   // [3][4]
  float* hbuf  = ws_f + 4096;   // [53248][3][128] f32 = 78.6 MB

  const size_t hbuf_floats = 53248ull * 3 * DD;           // 20,447,232
  const size_t bf_off_f    = 4096 + hbuf_floats;          // float offset
  ushort_t* item_bf = (ushort_t*)(ws_f + bf_off_f);       // 100000*128 u16
  ushort_t* loc_bf  = item_bf + 100000ull * DD;
  ushort_t* time_bf = loc_bf + 10000ull * DD;
  const size_t needed_full = (bf_off_f * 4) + (112000ull * DD * 2);

  const bool bf16_path = ws_size >= needed_full;

  hipMemsetAsync(d_ws, 0, 16384, stream);  // wsum accumulators

  if (bf16_path) {
    k_cvt<<<dim3((100000 * DD / 8 + 255) / 256), dim3(256), 0, stream>>>(item_emb, item_bf, 100000 * DD / 8);
    k_cvt<<<dim3((10000 * DD / 8 + 255) / 256), dim3(256), 0, stream>>>(loc_emb, loc_bf, 10000 * DD / 8);
    k_cvt<<<dim3((2000 * DD / 8 + 255) / 256), dim3(256), 0, stream>>>(time_emb, time_bf, 2000 * DD / 8);
  }

  k_sess<<<dim3(256), dim3(256), 0, stream>>>(session, hbuf);

  const dim3 blk(256);
  const int gi = 51200 / TRR, gs = 1024 / TRR;
  float* h_items = hbuf;
  float* h_locs  = hbuf + (size_t)51200 * 3 * DD;
  float* h_times = hbuf + (size_t)52224 * 3 * DD;

#define AGG(MODE, GRID, SELF, SELFB, SELFF, NB, EMBB, EMBF, Wm, Bm, WS, BS, Q, HD, WSUM, M) \
  k_agg2<MODE><<<dim3(GRID), blk, 0, stream>>>(SELF, SELFB, SELFF, NB, EMBB, EMBF, \
                                               Wm, Bm, WS, BS, Q, HD, WSUM, M)

  if (bf16_path) {
    AGG(1, gi, item, item_bf, nullptr, nb_II, item_bf, nullptr, W_II, b_II, Ws_i, bs_i, q_i, h_items + 0 * DD, wsum + 0, 0);
    AGG(1, gi, item, item_bf, nullptr, nb_TI, time_bf, nullptr, W_TI, b_TI, Ws_i, bs_i, q_i, h_items + 1 * DD, wsum + 0, 1);
    AGG(1, gi, item, item_bf, nullptr, nb_LI, loc_bf,  nullptr, W_LI, b_LI, Ws_i, bs_i, q_i, h_items + 2 * DD, wsum + 0, 2);
    AGG(1, gs, locs, loc_bf, nullptr, nb_IL, item_bf, nullptr, W_IL, b_IL, Ws_l, bs_l, q_l, h_locs + 0 * DD, wsum + 256, 0);
    AGG(1, gs, locs, loc_bf, nullptr, nb_TL, time_bf, nullptr, W_TL, b_TL, Ws_l, bs_l, q_l, h_locs + 1 * DD, wsum + 256, 1);
    AGG(1, gs, times, time_bf, nullptr, nb_IT, item_bf, nullptr, W_IT, b_IT, Ws_t, bs_t, q_t, h_times + 0 * DD, wsum + 512, 0);
    AGG(1, gs, times, time_bf, nullptr, nb_LT, loc_bf,  nullptr, W_LT, b_LT, Ws_t, bs_t, q_t, h_times + 1 * DD, wsum + 512, 1);
  } else {
    AGG(0, gi, item, nullptr, item_emb, nb_II, nullptr, item_emb, W_II, b_II, Ws_i, bs_i, q_i, h_items + 0 * DD, wsum + 0, 0);
    AGG(0, gi, item, nullptr, item_emb, nb_TI, nullptr, time_emb, W_TI, b_TI, Ws_i, bs_i, q_i, h_items + 1 * DD, wsum + 0, 1);
    AGG(0, gi, item, nullptr, item_emb, nb_LI, nullptr, loc_emb,  W_LI, b_LI, Ws_i, bs_i, q_i, h_items + 2 * DD, wsum + 0, 2);
    AGG(0, gs, locs, nullptr, loc_emb, nb_IL, nullptr, item_emb, W_IL, b_IL, Ws_l, bs_l, q_l, h_locs + 0 * DD, wsum + 256, 0);
    AGG(0, gs, locs, nullptr, loc_emb, nb_TL, nullptr, time_emb, W_TL, b_TL, Ws_l, bs_l, q_l, h_locs + 1 * DD, wsum + 256, 1);
    AGG(0, gs, times, nullptr, time_emb, nb_IT, nullptr, item_emb, W_IT, b_IT, Ws_t, bs_t, q_t, h_times + 0 * DD, wsum + 512, 0);
    AGG(0, gs, times, nullptr, time_emb, nb_LT, nullptr, loc_emb,  W_LT, b_LT, Ws_t, bs_t, q_t, h_times + 1 * DD, wsum + 512, 1);
  }
#undef AGG

  // session-row attention scores (m=2 for locs and times groups)
  k_wsess<<<dim3(64), blk, 0, stream>>>(session, Ws_l, bs_l, q_l, wsum + 256);
  k_wsess<<<dim3(64), blk, 0, stream>>>(session, Ws_t, bs_t, q_t, wsum + 512);

  k_beta<<<dim3(1), dim3(64), 0, stream>>>(wsum, betap);
  k_out<<<dim3((53248 * 128) / 256), dim3(256), 0, stream>>>(hbuf, betap, outp);
}

// Round 4
// 210.127 us; speedup vs baseline: 15.3698x; 2.9475x over previous
//
#include <hip/hip_runtime.h>
#include <hip/hip_fp16.h>

#define DD 128
#define KK 20
#define TRR 16

typedef unsigned int uint_t;
typedef unsigned short ushort_t;
typedef _Float16 f16x8 __attribute__((ext_vector_type(8)));
typedef float f32x4 __attribute__((ext_vector_type(4)));

union U16 {
  uint4 u4;
  __half2 h2[4];
};
union UH {
  __half h;
  ushort_t s;
};

__device__ __forceinline__ float fast_tanh(float x) {
  const float e = __expf(2.f * x);
  return 1.f - 2.f / (e + 1.f);
}

// ---------------------------------------------------------------------------
// f32 -> fp16 table conversion, 8 elems/thread
// ---------------------------------------------------------------------------
__global__ __launch_bounds__(256)
void k_cvt(const float* __restrict__ in, ushort_t* __restrict__ out, int n8) {
  const int t = blockIdx.x * blockDim.x + threadIdx.x;
  if (t >= n8) return;
  const float4* ip = reinterpret_cast<const float4*>(in + (size_t)t * 8);
  const float4 a = ip[0], b = ip[1];
  UH h[8];
  h[0].h = __float2half_rn(a.x); h[1].h = __float2half_rn(a.y);
  h[2].h = __float2half_rn(a.z); h[3].h = __float2half_rn(a.w);
  h[4].h = __float2half_rn(b.x); h[5].h = __float2half_rn(b.y);
  h[6].h = __float2half_rn(b.z); h[7].h = __float2half_rn(b.w);
  uint4 o;
  o.x = (uint_t)h[0].s | ((uint_t)h[1].s << 16);
  o.y = (uint_t)h[2].s | ((uint_t)h[3].s << 16);
  o.z = (uint_t)h[4].s | ((uint_t)h[5].s << 16);
  o.w = (uint_t)h[6].s | ((uint_t)h[7].s << 16);
  reinterpret_cast<uint4*>(out)[t] = o;
}

// ---------------------------------------------------------------------------
// Pack W[K][128] (f32) into MFMA B-fragment order, fp16.
// Fragment (kt, nt): lane l, reg j  <-  W[kt*32 + (l>>4)*8 + j][nt*16 + (l&15)]
// dst layout: [(kt*8 + nt)*512 + l*8 + j] halfs.
// ---------------------------------------------------------------------------
__global__ __launch_bounds__(256)
void k_pack(const float* __restrict__ W, ushort_t* __restrict__ dst, int ktiles) {
  const int t = blockIdx.x * blockDim.x + threadIdx.x;
  if (t >= ktiles * 8 * 64) return;
  const int l = t & 63;
  const int ktnt = t >> 6;
  const int kt = ktnt >> 3, nt = ktnt & 7;
  const int col = nt * 16 + (l & 15);
  const int kb = kt * 32 + ((l >> 4) << 3);
  UH h[8];
#pragma unroll
  for (int j = 0; j < 8; ++j) h[j].h = __float2half_rn(W[(size_t)(kb + j) * DD + col]);
  uint4 o;
  o.x = (uint_t)h[0].s | ((uint_t)h[1].s << 16);
  o.y = (uint_t)h[2].s | ((uint_t)h[3].s << 16);
  o.z = (uint_t)h[4].s | ((uint_t)h[5].s << 16);
  o.w = (uint_t)h[6].s | ((uint_t)h[7].s << 16);
  *reinterpret_cast<uint4*>(dst + (size_t)ktnt * 512 + l * 8) = o;
}

// ---------------------------------------------------------------------------
// k_agg3: one edge-type. 256 threads = 4 waves, 16 rows/block.
//  phase 1: gather self + fp16-packed neighbor mean -> xs[16][264] (pad 8)
//  phase 2: MFMA x[16x256] @ pW -> relu h [16x128]; store hbuf (fp16) + hs LDS
//  phase 3: MFMA h[16x128] @ pWs + bs -> tanh * q -> row sums -> atomicAdd
// ---------------------------------------------------------------------------
__global__ __launch_bounds__(256, 5)
void k_agg3(const int* __restrict__ self_idx,
            const ushort_t* __restrict__ self_t,
            const int* __restrict__ nb,
            const ushort_t* __restrict__ emb_t,
            const ushort_t* __restrict__ pW, const float* __restrict__ bias,
            const ushort_t* __restrict__ pWs, const float* __restrict__ bs,
            const float* __restrict__ q,
            ushort_t* __restrict__ hdst,
            float* __restrict__ wsum_g, int m) {
  __shared__ int ids[TRR];
  __shared__ int nidx[TRR][KK];
  __shared__ __align__(16) ushort_t xs[TRR][2 * DD + 8];   // 264, pad -> 2-way banks
  __shared__ __align__(16) ushort_t hs[TRR][DD + 8];       // 136
  __shared__ float red[4][TRR];

  const int tid = threadIdx.x;
  const int l = tid & 63;
  const int w = tid >> 6;
  const int n0 = blockIdx.x * TRR;

  if (tid < TRR) ids[tid] = self_idx[n0 + tid];
  __syncthreads();

  const int gr = tid >> 4;        // 0..15 row
  const int gsl = tid & 15;       // 16B slice

  for (int t = tid; t < TRR * KK; t += 256) {
    const int rr = t / KK, kk = t - rr * KK;
    nidx[rr][kk] = nb[(size_t)ids[rr] * KK + kk];
  }

  // self half
  *reinterpret_cast<uint4*>(&xs[gr][gsl * 8]) =
      *reinterpret_cast<const uint4*>(self_t + ((size_t)ids[gr] << 7) + gsl * 8);
  __syncthreads();

  // neighbor mean in packed half2
  {
    U16 acc;
    const __half2 z = __float2half2_rn(0.f);
    acc.h2[0] = z; acc.h2[1] = z; acc.h2[2] = z; acc.h2[3] = z;
#pragma unroll 10
    for (int k = 0; k < KK; ++k) {
      U16 v;
      v.u4 = *reinterpret_cast<const uint4*>(emb_t + ((size_t)nidx[gr][k] << 7) + gsl * 8);
      acc.h2[0] = __hadd2(acc.h2[0], v.h2[0]);
      acc.h2[1] = __hadd2(acc.h2[1], v.h2[1]);
      acc.h2[2] = __hadd2(acc.h2[2], v.h2[2]);
      acc.h2[3] = __hadd2(acc.h2[3], v.h2[3]);
    }
    const __half2 sc = __float2half2_rn(1.f / KK);
    acc.h2[0] = __hmul2(acc.h2[0], sc);
    acc.h2[1] = __hmul2(acc.h2[1], sc);
    acc.h2[2] = __hmul2(acc.h2[2], sc);
    acc.h2[3] = __hmul2(acc.h2[3], sc);
    *reinterpret_cast<uint4*>(&xs[gr][DD + gsl * 8]) = acc.u4;
  }
  __syncthreads();

  // phase 2: MFMA. wave w covers ntiles {2w, 2w+1} (cols w*32 .. w*32+31)
  const int nt0 = 2 * w;
  const int lcol = l & 15;
  const int g8 = (l >> 4) << 3;
  const int col0 = nt0 * 16 + lcol;
  const int col1 = col0 + 16;
  f32x4 acc0, acc1;
  {
    const float b0 = bias[col0], b1 = bias[col1];
    acc0 = (f32x4){b0, b0, b0, b0};
    acc1 = (f32x4){b1, b1, b1, b1};
#pragma unroll
    for (int kt = 0; kt < 8; ++kt) {
      const f16x8 A = *reinterpret_cast<const f16x8*>(
          (const void*)&xs[lcol][kt * 32 + g8]);
      const f16x8 B0 = *reinterpret_cast<const f16x8*>(
          (const void*)(pW + ((size_t)(kt * 8 + nt0) * 512) + l * 8));
      const f16x8 B1 = *reinterpret_cast<const f16x8*>(
          (const void*)(pW + ((size_t)(kt * 8 + nt0 + 1) * 512) + l * 8));
      acc0 = __builtin_amdgcn_mfma_f32_16x16x32_f16(A, B0, acc0, 0, 0, 0);
      acc1 = __builtin_amdgcn_mfma_f32_16x16x32_f16(A, B1, acc1, 0, 0, 0);
    }
#pragma unroll
    for (int j = 0; j < 4; ++j) {
      acc0[j] = fmaxf(acc0[j], 0.f);
      acc1[j] = fmaxf(acc1[j], 0.f);
    }
  }

  // store h: C layout col = l&15 (+16*nt), row = (l>>4)*4 + j   [HW-verified]
  {
    const int rbase = (l >> 4) << 2;
#pragma unroll
    for (int j = 0; j < 4; ++j) {
      const int row = rbase + j;
      UH h0, h1;
      h0.h = __float2half_rn(acc0[j]);
      h1.h = __float2half_rn(acc1[j]);
      hdst[(size_t)(n0 + row) * 3 * DD + col0] = h0.s;
      hdst[(size_t)(n0 + row) * 3 * DD + col1] = h1.s;
      hs[row][col0] = h0.s;
      hs[row][col1] = h1.s;
    }
  }
  __syncthreads();

  // phase 3: t = h @ Ws + bs (MFMA, K=128), w-score = sum_col tanh(t)*q
  {
    const float b0 = bs[col0], b1 = bs[col1];
    f32x4 s0 = (f32x4){b0, b0, b0, b0};
    f32x4 s1 = (f32x4){b1, b1, b1, b1};
#pragma unroll
    for (int kt = 0; kt < 4; ++kt) {
      const f16x8 A = *reinterpret_cast<const f16x8*>(
          (const void*)&hs[lcol][kt * 32 + g8]);
      const f16x8 B0 = *reinterpret_cast<const f16x8*>(
          (const void*)(pWs + ((size_t)(kt * 8 + nt0) * 512) + l * 8));
      const f16x8 B1 = *reinterpret_cast<const f16x8*>(
          (const void*)(pWs + ((size_t)(kt * 8 + nt0 + 1) * 512) + l * 8));
      s0 = __builtin_amdgcn_mfma_f32_16x16x32_f16(A, B0, s0, 0, 0, 0);
      s1 = __builtin_amdgcn_mfma_f32_16x16x32_f16(A, B1, s1, 0, 0, 0);
    }
    const float q0 = q[col0], q1 = q[col1];
    float p[4];
#pragma unroll
    for (int j = 0; j < 4; ++j)
      p[j] = fast_tanh(s0[j]) * q0 + fast_tanh(s1[j]) * q1;
    // sum over the 16 lanes of each column group (same l>>4)
#pragma unroll
    for (int off = 1; off < 16; off <<= 1) {
#pragma unroll
      for (int j = 0; j < 4; ++j) p[j] += __shfl_xor(p[j], off, 64);
    }
    if (lcol == 0) {
      const int rbase = (l >> 4) << 2;
#pragma unroll
      for (int j = 0; j < 4; ++j) red[w][rbase + j] = p[j];
    }
  }
  __syncthreads();
  if (tid < TRR) {
    float s = red[0][tid] + red[1][tid] + red[2][tid] + red[3][tid];
#pragma unroll
    for (int off = 1; off < 16; off <<= 1) s += __shfl_xor(s, off, 64);
    if (tid == 0) atomicAdd(&wsum_g[(blockIdx.x & 63) * 4 + m], s);
  }
}

// ---------------------------------------------------------------------------
// w scores for session rows (reads f32 session input); bucket m=2
// ---------------------------------------------------------------------------
__device__ __forceinline__ float4 f4fma(float s, float4 a, float4 b) {
  b.x = fmaf(s, a.x, b.x); b.y = fmaf(s, a.y, b.y);
  b.z = fmaf(s, a.z, b.z); b.w = fmaf(s, a.w, b.w);
  return b;
}

__global__ __launch_bounds__(256, 4)
void k_wsess(const float* __restrict__ hsrc, const float* __restrict__ Ws,
             const float* __restrict__ bsv, const float* __restrict__ q,
             float* __restrict__ wsum_g) {
  __shared__ __align__(16) float hsh[TRR][DD];
  __shared__ float red[TRR];
  const int tid = threadIdx.x;
  const int h0 = blockIdx.x * TRR;
  {
    const int r = tid >> 4, c = (tid & 15) * 8;
    const float4* sp = reinterpret_cast<const float4*>(hsrc + (size_t)(h0 + r) * DD + c);
    *reinterpret_cast<float4*>(&hsh[r][c])     = sp[0];
    *reinterpret_cast<float4*>(&hsh[r][c + 4]) = sp[1];
  }
  __syncthreads();
  const int tx = tid & 31, ty = tid >> 5;
  const int c0 = tx * 4;
  const int r0 = 2 * ty, r1 = r0 + 1;
  const float4 bv = *reinterpret_cast<const float4*>(bsv + c0);
  float4 s0 = bv, s1 = bv;
  const float* Wp = Ws + c0;
#pragma unroll 2
  for (int j = 0; j < DD; j += 4) {
    const float4 w0 = *reinterpret_cast<const float4*>(Wp + (size_t)(j + 0) * DD);
    const float4 w1 = *reinterpret_cast<const float4*>(Wp + (size_t)(j + 1) * DD);
    const float4 w2 = *reinterpret_cast<const float4*>(Wp + (size_t)(j + 2) * DD);
    const float4 w3 = *reinterpret_cast<const float4*>(Wp + (size_t)(j + 3) * DD);
    const float4 xa = *reinterpret_cast<const float4*>(&hsh[r0][j]);
    const float4 xb = *reinterpret_cast<const float4*>(&hsh[r1][j]);
    s0 = f4fma(xa.x, w0, s0); s0 = f4fma(xa.y, w1, s0);
    s0 = f4fma(xa.z, w2, s0); s0 = f4fma(xa.w, w3, s0);
    s1 = f4fma(xb.x, w0, s1); s1 = f4fma(xb.y, w1, s1);
    s1 = f4fma(xb.z, w2, s1); s1 = f4fma(xb.w, w3, s1);
  }
  const float4 qv = *reinterpret_cast<const float4*>(q + c0);
  float v0 = fast_tanh(s0.x) * qv.x + fast_tanh(s0.y) * qv.y +
             fast_tanh(s0.z) * qv.z + fast_tanh(s0.w) * qv.w;
  float v1 = fast_tanh(s1.x) * qv.x + fast_tanh(s1.y) * qv.y +
             fast_tanh(s1.z) * qv.z + fast_tanh(s1.w) * qv.w;
#pragma unroll
  for (int off = 1; off < 32; off <<= 1) {
    v0 += __shfl_xor(v0, off, 64);
    v1 += __shfl_xor(v1, off, 64);
  }
  if (tx == 0) { red[r0] = v0; red[r1] = v1; }
  __syncthreads();
  if (tid == 0) {
    float c = 0.f;
#pragma unroll
    for (int r = 0; r < TRR; ++r) c += red[r];
    atomicAdd(&wsum_g[(blockIdx.x & 63) * 4 + 2], c);
  }
}

// session rows -> hbuf fp16 at [(51200+n)*3+2] and [(52224+n)*3+2]
__global__ void k_sess(const float* __restrict__ session, ushort_t* __restrict__ hbuf) {
  const int t = blockIdx.x * blockDim.x + threadIdx.x;  // 65536 threads, 4 elems each
  const int row = t >> 5;          // 0..2047
  const int c0 = (t & 31) * 4;
  const int n = row & 1023;
  const size_t grow = (row < 1024) ? (size_t)(51200 + n) : (size_t)(52224 + n);
  const float4 v = *reinterpret_cast<const float4*>(session + (size_t)n * DD + c0);
  UH h0, h1, h2, h3;
  h0.h = __float2half_rn(v.x); h1.h = __float2half_rn(v.y);
  h2.h = __float2half_rn(v.z); h3.h = __float2half_rn(v.w);
  ushort4 o; o.x = h0.s; o.y = h1.s; o.z = h2.s; o.w = h3.s;
  *reinterpret_cast<ushort4*>(hbuf + (grow * 3 + 2) * DD + c0) = o;
}

__global__ void k_beta(const float* __restrict__ wsum, float* __restrict__ beta) {
  if (threadIdx.x == 0 && blockIdx.x == 0) {
    const float invN[3] = {1.f / 51200.f, 1.f / 1024.f, 1.f / 1024.f};
    for (int g = 0; g < 3; ++g) {
      float s0 = 0.f, s1 = 0.f, s2 = 0.f;
      for (int bkt = 0; bkt < 64; ++bkt) {
        s0 += wsum[g * 256 + bkt * 4 + 0];
        s1 += wsum[g * 256 + bkt * 4 + 1];
        s2 += wsum[g * 256 + bkt * 4 + 2];
      }
      s0 *= invN[g]; s1 *= invN[g]; s2 *= invN[g];
      const float mx = fmaxf(s0, fmaxf(s1, s2));
      const float e0 = expf(s0 - mx), e1 = expf(s1 - mx), e2 = expf(s2 - mx);
      const float inv = 1.f / (e0 + e1 + e2);
      beta[g * 4 + 0] = e0 * inv;
      beta[g * 4 + 1] = e1 * inv;
      beta[g * 4 + 2] = e2 * inv;
    }
  }
}

// out[row,d] = sum_m beta[g(row)][m] * h[row,m,d]  (h fp16)
__global__ void k_out(const ushort_t* __restrict__ h, const float* __restrict__ beta,
                      float* __restrict__ out) {
  const int idx = blockIdx.x * blockDim.x + threadIdx.x;
  const int row = idx >> 7;
  const int g = (row < 51200) ? 0 : ((row < 52224) ? 1 : 2);
  const float* bt = beta + g * 4;
  const size_t base = (size_t)idx + (size_t)row * 2 * DD;
  UH a, b, c;
  a.s = h[base]; b.s = h[base + DD]; c.s = h[base + 2 * DD];
  out[idx] = bt[0] * __half2float(a.h) + bt[1] * __half2float(b.h) +
             bt[2] * __half2float(c.h);
}

// ---------------------------------------------------------------------------

extern "C" void kernel_launch(void* const* d_in, const int* in_sizes, int n_in,
                              void* d_out, int out_size, void* d_ws, size_t ws_size,
                              hipStream_t stream) {
  const int*   item     = (const int*)  d_in[0];
  const int*   locs     = (const int*)  d_in[1];
  const int*   times    = (const int*)  d_in[2];
  const float* session  = (const float*)d_in[3];
  const float* loc_emb  = (const float*)d_in[4];
  const float* time_emb = (const float*)d_in[5];
  const float* item_emb = (const float*)d_in[6];
  const int* nb_IL = (const int*)d_in[7];
  const int* nb_TL = (const int*)d_in[8];
  const int* nb_IT = (const int*)d_in[9];
  const int* nb_LT = (const int*)d_in[10];
  const int* nb_II = (const int*)d_in[11];
  const int* nb_LI = (const int*)d_in[12];
  const int* nb_TI = (const int*)d_in[13];
  const float* W_IL = (const float*)d_in[14]; const float* b_IL = (const float*)d_in[15];
  const float* W_TL = (const float*)d_in[16]; const float* b_TL = (const float*)d_in[17];
  const float* W_IT = (const float*)d_in[18]; const float* b_IT = (const float*)d_in[19];
  const float* W_LT = (const float*)d_in[20]; const float* b_LT = (const float*)d_in[21];
  const float* W_II = (const float*)d_in[22]; const float* b_II = (const float*)d_in[23];
  const float* W_LI = (const float*)d_in[24]; const float* b_LI = (const float*)d_in[25];
  const float* W_TI = (const float*)d_in[26]; const float* b_TI = (const float*)d_in[27];
  const float* Ws_l = (const float*)d_in[28]; const float* bs_l = (const float*)d_in[29];
  const float* q_l  = (const float*)d_in[30];
  const float* Ws_t = (const float*)d_in[31]; const float* bs_t = (const float*)d_in[32];
  const float* q_t  = (const float*)d_in[33];
  const float* Ws_i = (const float*)d_in[34]; const float* bs_i = (const float*)d_in[35];
  const float* q_i  = (const float*)d_in[36];

  float* outp = (float*)d_out;

  // ws layout (bytes):
  //   [0, 16K)    : wsum[3][64][4] f32 + betap[3][4] f32 (at float idx 1024)
  //   [16K, +544K): packed weights fp16: 7 x 64KB (W) + 3 x 32KB (Ws)
  //   then hbuf fp16 [53248][3][128]  (40.9 MB)
  //   then fp16 tables: item(25.6MB), loc(2.56MB), time(0.51MB)
  char* wsb = (char*)d_ws;
  float* wsum  = (float*)wsb;
  float* betap = (float*)wsb + 1024;
  ushort_t* pk = (ushort_t*)(wsb + 16384);
  ushort_t* pk_II = pk;                 // 32768 halfs each (64KB)
  ushort_t* pk_TI = pk_II + 32768;
  ushort_t* pk_LI = pk_TI + 32768;
  ushort_t* pk_IL = pk_LI + 32768;
  ushort_t* pk_TL = pk_IL + 32768;
  ushort_t* pk_IT = pk_TL + 32768;
  ushort_t* pk_LT = pk_IT + 32768;
  ushort_t* pk_Wi = pk_LT + 32768;      // 16384 halfs each (32KB)
  ushort_t* pk_Wl = pk_Wi + 16384;
  ushort_t* pk_Wt = pk_Wl + 16384;
  ushort_t* hbuf  = pk_Wt + 16384;                    // 53248*384 halfs
  ushort_t* item_h = hbuf + (size_t)53248 * 3 * DD;   // 12.8M halfs
  ushort_t* loc_h  = item_h + (size_t)100000 * DD;
  ushort_t* time_h = loc_h + (size_t)10000 * DD;

  hipMemsetAsync(d_ws, 0, 16384, stream);  // zero wsum accumulators

  // table conversions
  k_cvt<<<dim3((100000 * DD / 8 + 255) / 256), dim3(256), 0, stream>>>(item_emb, item_h, 100000 * DD / 8);
  k_cvt<<<dim3((10000 * DD / 8 + 255) / 256), dim3(256), 0, stream>>>(loc_emb, loc_h, 10000 * DD / 8);
  k_cvt<<<dim3((2000 * DD / 8 + 255) / 256), dim3(256), 0, stream>>>(time_emb, time_h, 2000 * DD / 8);

  // weight packing: edge W (K=256 -> 8 ktiles, 4096 threads), Ws (K=128 -> 2048)
  k_pack<<<dim3(16), dim3(256), 0, stream>>>(W_II, pk_II, 8);
  k_pack<<<dim3(16), dim3(256), 0, stream>>>(W_TI, pk_TI, 8);
  k_pack<<<dim3(16), dim3(256), 0, stream>>>(W_LI, pk_LI, 8);
  k_pack<<<dim3(16), dim3(256), 0, stream>>>(W_IL, pk_IL, 8);
  k_pack<<<dim3(16), dim3(256), 0, stream>>>(W_TL, pk_TL, 8);
  k_pack<<<dim3(16), dim3(256), 0, stream>>>(W_IT, pk_IT, 8);
  k_pack<<<dim3(16), dim3(256), 0, stream>>>(W_LT, pk_LT, 8);
  k_pack<<<dim3(8),  dim3(256), 0, stream>>>(Ws_i, pk_Wi, 4);
  k_pack<<<dim3(8),  dim3(256), 0, stream>>>(Ws_l, pk_Wl, 4);
  k_pack<<<dim3(8),  dim3(256), 0, stream>>>(Ws_t, pk_Wt, 4);

  k_sess<<<dim3(256), dim3(256), 0, stream>>>(session, hbuf);

  const dim3 blk(256);
  const int gi = 51200 / TRR, gs = 1024 / TRR;
  ushort_t* h_items = hbuf;
  ushort_t* h_locs  = hbuf + (size_t)51200 * 3 * DD;
  ushort_t* h_times = hbuf + (size_t)52224 * 3 * DD;

  // items: m = [II, TI, LI]
  k_agg3<<<dim3(gi), blk, 0, stream>>>(item, item_h, nb_II, item_h, pk_II, b_II,
                                       pk_Wi, bs_i, q_i, h_items + 0 * DD, wsum + 0, 0);
  k_agg3<<<dim3(gi), blk, 0, stream>>>(item, item_h, nb_TI, time_h, pk_TI, b_TI,
                                       pk_Wi, bs_i, q_i, h_items + 1 * DD, wsum + 0, 1);
  k_agg3<<<dim3(gi), blk, 0, stream>>>(item, item_h, nb_LI, loc_h, pk_LI, b_LI,
                                       pk_Wi, bs_i, q_i, h_items + 2 * DD, wsum + 0, 2);
  // locs: m = [IL, TL]
  k_agg3<<<dim3(gs), blk, 0, stream>>>(locs, loc_h, nb_IL, item_h, pk_IL, b_IL,
                                       pk_Wl, bs_l, q_l, h_locs + 0 * DD, wsum + 256, 0);
  k_agg3<<<dim3(gs), blk, 0, stream>>>(locs, loc_h, nb_TL, time_h, pk_TL, b_TL,
                                       pk_Wl, bs_l, q_l, h_locs + 1 * DD, wsum + 256, 1);
  // times: m = [IT, LT]
  k_agg3<<<dim3(gs), blk, 0, stream>>>(times, time_h, nb_IT, item_h, pk_IT, b_IT,
                                       pk_Wt, bs_t, q_t, h_times + 0 * DD, wsum + 512, 0);
  k_agg3<<<dim3(gs), blk, 0, stream>>>(times, time_h, nb_LT, loc_h, pk_LT, b_LT,
                                       pk_Wt, bs_t, q_t, h_times + 1 * DD, wsum + 512, 1);

  // session-row scores (m=2 of locs/times groups)
  k_wsess<<<dim3(64), blk, 0, stream>>>(session, Ws_l, bs_l, q_l, wsum + 256);
  k_wsess<<<dim3(64), blk, 0, stream>>>(session, Ws_t, bs_t, q_t, wsum + 512);

  k_beta<<<dim3(1), dim3(64), 0, stream>>>(wsum, betap);
  k_out<<<dim3((53248 * 128) / 256), dim3(256), 0, stream>>>(hbuf, betap, outp);
}

// Round 5
// 166.645 us; speedup vs baseline: 19.3803x; 1.2609x over previous
//
#include <hip/hip_runtime.h>
#include <hip/hip_fp16.h>

#define DD 128
#define KK 20
#define TRR 16

typedef unsigned int uint_t;
typedef unsigned short ushort_t;
typedef _Float16 f16x8 __attribute__((ext_vector_type(8)));
typedef float f32x4 __attribute__((ext_vector_type(4)));

union U16 { uint4 u4; __half2 h2[4]; };
union UH { __half h; ushort_t s; };

__device__ __forceinline__ float fast_tanh(float x) {
  const float e = __expf(2.f * x);
  return 1.f - 2.f / (e + 1.f);
}

// ---------------------------------------------------------------------------
// k_cvt3: all three f32 tables -> contiguous fp16 region. 8 elems/thread.
// thread ranges: [0,1.6M) item, [1.6M,1.76M) loc, [1.76M,1.792M) time.
// ---------------------------------------------------------------------------
struct CvtArgs {
  const float* item; const float* loc; const float* timet;
  ushort_t* dst;
};

__global__ __launch_bounds__(256)
void k_cvt3(CvtArgs a) {
  const int t = blockIdx.x * blockDim.x + threadIdx.x;  // 7000*256 = 1,792,000
  const float* src;
  if (t < 1600000) src = a.item + (size_t)t * 8;
  else if (t < 1760000) src = a.loc + ((size_t)t - 1600000) * 8;
  else src = a.timet + ((size_t)t - 1760000) * 8;
  const float4* ip = reinterpret_cast<const float4*>(src);
  const float4 x = ip[0], y = ip[1];
  UH h[8];
  h[0].h = __float2half_rn(x.x); h[1].h = __float2half_rn(x.y);
  h[2].h = __float2half_rn(x.z); h[3].h = __float2half_rn(x.w);
  h[4].h = __float2half_rn(y.x); h[5].h = __float2half_rn(y.y);
  h[6].h = __float2half_rn(y.z); h[7].h = __float2half_rn(y.w);
  uint4 o;
  o.x = (uint_t)h[0].s | ((uint_t)h[1].s << 16);
  o.y = (uint_t)h[2].s | ((uint_t)h[3].s << 16);
  o.z = (uint_t)h[4].s | ((uint_t)h[5].s << 16);
  o.w = (uint_t)h[6].s | ((uint_t)h[7].s << 16);
  reinterpret_cast<uint4*>(a.dst)[t] = o;
}

// ---------------------------------------------------------------------------
// k_pack10: all 10 weight matrices -> MFMA B-fragment order fp16, one launch.
// jobs 0..6: W (K=256, 8 ktiles, 16 blocks each); 7..9: Ws (K=128, 8 blocks).
// Fragment (kt,nt): lane l, reg j <- W[kt*32 + (l>>4)*8 + j][nt*16 + (l&15)]
// ---------------------------------------------------------------------------
struct PackArgs {
  const float* src[10];
  ushort_t* dst;
};

__global__ __launch_bounds__(256)
void k_pack10(PackArgs a) {
  const int b = blockIdx.x, tid = threadIdx.x;
  int job, tin;
  size_t doff;
  if (b < 112) {
    job = b >> 4; tin = ((b & 15) << 8) | tid;
    doff = (size_t)job * 32768;
  } else {
    job = 7 + ((b - 112) >> 3); tin = (((b - 112) & 7) << 8) | tid;
    doff = 7ull * 32768 + (size_t)(job - 7) * 16384;
  }
  const float* W = a.src[job];
  const int l = tin & 63;
  const int ktnt = tin >> 6;
  const int nt = ktnt & 7;
  const int kt = ktnt >> 3;
  const int col = nt * 16 + (l & 15);
  const int kb = kt * 32 + ((l >> 4) << 3);
  UH h[8];
#pragma unroll
  for (int j = 0; j < 8; ++j) h[j].h = __float2half_rn(W[(size_t)(kb + j) * DD + col]);
  uint4 o;
  o.x = (uint_t)h[0].s | ((uint_t)h[1].s << 16);
  o.y = (uint_t)h[2].s | ((uint_t)h[3].s << 16);
  o.z = (uint_t)h[4].s | ((uint_t)h[5].s << 16);
  o.w = (uint_t)h[6].s | ((uint_t)h[7].s << 16);
  *reinterpret_cast<uint4*>(a.dst + doff + (size_t)ktnt * 512 + l * 8) = o;
}

// ---------------------------------------------------------------------------
// k_aggI: items group, all 3 edges fused. 256 threads, 16 rows/block.
// per edge: gather-mean -> MFMA(x@W)+relu -> store h -> MFMA(h@Ws) w-score.
// ---------------------------------------------------------------------------
struct AggIArgs {
  const int* self_idx;
  const ushort_t* self_t;
  const int* nb[3];
  const ushort_t* emb[3];
  const ushort_t* pW[3];
  const float* bias[3];
  const ushort_t* pWs; const float* bs; const float* q;
  ushort_t* hdst; float* wsum;
};

__global__ __launch_bounds__(256, 4)
void k_aggI(AggIArgs a) {
  __shared__ int ids[TRR];
  __shared__ int nidx[3][TRR][KK];
  __shared__ __align__(16) ushort_t xs[TRR][2 * DD + 8];
  __shared__ __align__(16) ushort_t hs[TRR][DD + 8];
  __shared__ float red[4][TRR];

  const int tid = threadIdx.x;
  const int l = tid & 63;
  const int w = tid >> 6;
  const int n0 = blockIdx.x * TRR;

  if (tid < TRR) ids[tid] = a.self_idx[n0 + tid];
  __syncthreads();

  const int gr = tid >> 4;
  const int gsl = tid & 15;

#pragma unroll
  for (int e = 0; e < 3; ++e) {
    const int* nbp = a.nb[e];
    for (int t = tid; t < TRR * KK; t += 256) {
      const int rr = t / KK, kk = t - rr * KK;
      nidx[e][rr][kk] = nbp[(size_t)ids[rr] * KK + kk];
    }
  }
  // self half of x (shared by all 3 edges)
  *reinterpret_cast<uint4*>(&xs[gr][gsl * 8]) =
      *reinterpret_cast<const uint4*>(a.self_t + ((size_t)ids[gr] << 7) + gsl * 8);
  __syncthreads();

  const int nt0 = 2 * w;
  const int lcol = l & 15;
  const int g8 = (l >> 4) << 3;
  const int col0 = nt0 * 16 + lcol;
  const int col1 = col0 + 16;

#pragma unroll
  for (int e = 0; e < 3; ++e) {
    const ushort_t* embp = a.emb[e];
    const ushort_t* pWp = a.pW[e];
    const float* bp = a.bias[e];

    // neighbor mean (packed half2)
    {
      U16 acc;
      const __half2 z = __float2half2_rn(0.f);
      acc.h2[0] = z; acc.h2[1] = z; acc.h2[2] = z; acc.h2[3] = z;
#pragma unroll 10
      for (int k = 0; k < KK; ++k) {
        U16 v;
        v.u4 = *reinterpret_cast<const uint4*>(embp + ((size_t)nidx[e][gr][k] << 7) + gsl * 8);
        acc.h2[0] = __hadd2(acc.h2[0], v.h2[0]);
        acc.h2[1] = __hadd2(acc.h2[1], v.h2[1]);
        acc.h2[2] = __hadd2(acc.h2[2], v.h2[2]);
        acc.h2[3] = __hadd2(acc.h2[3], v.h2[3]);
      }
      const __half2 sc = __float2half2_rn(1.f / KK);
      acc.h2[0] = __hmul2(acc.h2[0], sc);
      acc.h2[1] = __hmul2(acc.h2[1], sc);
      acc.h2[2] = __hmul2(acc.h2[2], sc);
      acc.h2[3] = __hmul2(acc.h2[3], sc);
      *reinterpret_cast<uint4*>(&xs[gr][DD + gsl * 8]) = acc.u4;
    }
    __syncthreads();

    // MFMA: h = relu(x @ W + b)
    f32x4 acc0, acc1;
    {
      const float b0 = bp[col0], b1 = bp[col1];
      acc0 = (f32x4){b0, b0, b0, b0};
      acc1 = (f32x4){b1, b1, b1, b1};
#pragma unroll
      for (int kt = 0; kt < 8; ++kt) {
        const f16x8 A = *reinterpret_cast<const f16x8*>((const void*)&xs[lcol][kt * 32 + g8]);
        const f16x8 B0 = *reinterpret_cast<const f16x8*>(
            (const void*)(pWp + ((size_t)(kt * 8 + nt0) * 512) + l * 8));
        const f16x8 B1 = *reinterpret_cast<const f16x8*>(
            (const void*)(pWp + ((size_t)(kt * 8 + nt0 + 1) * 512) + l * 8));
        acc0 = __builtin_amdgcn_mfma_f32_16x16x32_f16(A, B0, acc0, 0, 0, 0);
        acc1 = __builtin_amdgcn_mfma_f32_16x16x32_f16(A, B1, acc1, 0, 0, 0);
      }
#pragma unroll
      for (int j = 0; j < 4; ++j) {
        acc0[j] = fmaxf(acc0[j], 0.f);
        acc1[j] = fmaxf(acc1[j], 0.f);
      }
    }

    // store h (C layout: col=l&15 (+16*nt), row=(l>>4)*4+j) to hbuf + hs LDS
    {
      const int rbase = (l >> 4) << 2;
#pragma unroll
      for (int j = 0; j < 4; ++j) {
        const int row = rbase + j;
        UH h0, h1;
        h0.h = __float2half_rn(acc0[j]);
        h1.h = __float2half_rn(acc1[j]);
        a.hdst[(size_t)(n0 + row) * 3 * DD + e * DD + col0] = h0.s;
        a.hdst[(size_t)(n0 + row) * 3 * DD + e * DD + col1] = h1.s;
        hs[row][col0] = h0.s;
        hs[row][col1] = h1.s;
      }
    }
    __syncthreads();

    // w-score: t = h @ Ws + bs; w = sum tanh(t)*q
    {
      const float b0 = a.bs[col0], b1 = a.bs[col1];
      f32x4 s0 = (f32x4){b0, b0, b0, b0};
      f32x4 s1 = (f32x4){b1, b1, b1, b1};
#pragma unroll
      for (int kt = 0; kt < 4; ++kt) {
        const f16x8 A = *reinterpret_cast<const f16x8*>((const void*)&hs[lcol][kt * 32 + g8]);
        const f16x8 B0 = *reinterpret_cast<const f16x8*>(
            (const void*)(a.pWs + ((size_t)(kt * 8 + nt0) * 512) + l * 8));
        const f16x8 B1 = *reinterpret_cast<const f16x8*>(
            (const void*)(a.pWs + ((size_t)(kt * 8 + nt0 + 1) * 512) + l * 8));
        s0 = __builtin_amdgcn_mfma_f32_16x16x32_f16(A, B0, s0, 0, 0, 0);
        s1 = __builtin_amdgcn_mfma_f32_16x16x32_f16(A, B1, s1, 0, 0, 0);
      }
      const float q0 = a.q[col0], q1 = a.q[col1];
      float p[4];
#pragma unroll
      for (int j = 0; j < 4; ++j)
        p[j] = fast_tanh(s0[j]) * q0 + fast_tanh(s1[j]) * q1;
#pragma unroll
      for (int off = 1; off < 16; off <<= 1) {
#pragma unroll
        for (int j = 0; j < 4; ++j) p[j] += __shfl_xor(p[j], off, 64);
      }
      if (lcol == 0) {
        const int rbase = (l >> 4) << 2;
#pragma unroll
        for (int j = 0; j < 4; ++j) red[w][rbase + j] = p[j];
      }
    }
    __syncthreads();
    if (tid < TRR) {
      float s = red[0][tid] + red[1][tid] + red[2][tid] + red[3][tid];
#pragma unroll
      for (int off = 1; off < 16; off <<= 1) s += __shfl_xor(s, off, 64);
      if (tid == 0) atomicAdd(&a.wsum[(blockIdx.x & 63) * 4 + e], s);
    }
    __syncthreads();
  }
}

// ---------------------------------------------------------------------------
// k_aggS: locs/times group fused — 2 edges + session passthrough + scores.
// ---------------------------------------------------------------------------
struct AggSArgs {
  const int* self_idx;
  const ushort_t* self_t;
  const int* nb[2];
  const ushort_t* emb[2];
  const ushort_t* pW[2];
  const float* bias[2];
  const ushort_t* pWs; const float* bs; const float* q;
  const float* session;
  ushort_t* hdst; float* wsum;
};

__global__ __launch_bounds__(256, 4)
void k_aggS(AggSArgs a) {
  __shared__ int ids[TRR];
  __shared__ int nidx[2][TRR][KK];
  __shared__ __align__(16) ushort_t xs[TRR][2 * DD + 8];
  __shared__ __align__(16) ushort_t hs[TRR][DD + 8];
  __shared__ float red[4][TRR];

  const int tid = threadIdx.x;
  const int l = tid & 63;
  const int w = tid >> 6;
  const int n0 = blockIdx.x * TRR;

  if (tid < TRR) ids[tid] = a.self_idx[n0 + tid];
  __syncthreads();

  const int gr = tid >> 4;
  const int gsl = tid & 15;

#pragma unroll
  for (int e = 0; e < 2; ++e) {
    const int* nbp = a.nb[e];
    for (int t = tid; t < TRR * KK; t += 256) {
      const int rr = t / KK, kk = t - rr * KK;
      nidx[e][rr][kk] = nbp[(size_t)ids[rr] * KK + kk];
    }
  }
  *reinterpret_cast<uint4*>(&xs[gr][gsl * 8]) =
      *reinterpret_cast<const uint4*>(a.self_t + ((size_t)ids[gr] << 7) + gsl * 8);
  __syncthreads();

  const int nt0 = 2 * w;
  const int lcol = l & 15;
  const int g8 = (l >> 4) << 3;
  const int col0 = nt0 * 16 + lcol;
  const int col1 = col0 + 16;

#pragma unroll
  for (int e = 0; e < 2; ++e) {
    const ushort_t* embp = a.emb[e];
    const ushort_t* pWp = a.pW[e];
    const float* bp = a.bias[e];
    {
      U16 acc;
      const __half2 z = __float2half2_rn(0.f);
      acc.h2[0] = z; acc.h2[1] = z; acc.h2[2] = z; acc.h2[3] = z;
#pragma unroll 10
      for (int k = 0; k < KK; ++k) {
        U16 v;
        v.u4 = *reinterpret_cast<const uint4*>(embp + ((size_t)nidx[e][gr][k] << 7) + gsl * 8);
        acc.h2[0] = __hadd2(acc.h2[0], v.h2[0]);
        acc.h2[1] = __hadd2(acc.h2[1], v.h2[1]);
        acc.h2[2] = __hadd2(acc.h2[2], v.h2[2]);
        acc.h2[3] = __hadd2(acc.h2[3], v.h2[3]);
      }
      const __half2 sc = __float2half2_rn(1.f / KK);
      acc.h2[0] = __hmul2(acc.h2[0], sc);
      acc.h2[1] = __hmul2(acc.h2[1], sc);
      acc.h2[2] = __hmul2(acc.h2[2], sc);
      acc.h2[3] = __hmul2(acc.h2[3], sc);
      *reinterpret_cast<uint4*>(&xs[gr][DD + gsl * 8]) = acc.u4;
    }
    __syncthreads();

    f32x4 acc0, acc1;
    {
      const float b0 = bp[col0], b1 = bp[col1];
      acc0 = (f32x4){b0, b0, b0, b0};
      acc1 = (f32x4){b1, b1, b1, b1};
#pragma unroll
      for (int kt = 0; kt < 8; ++kt) {
        const f16x8 A = *reinterpret_cast<const f16x8*>((const void*)&xs[lcol][kt * 32 + g8]);
        const f16x8 B0 = *reinterpret_cast<const f16x8*>(
            (const void*)(pWp + ((size_t)(kt * 8 + nt0) * 512) + l * 8));
        const f16x8 B1 = *reinterpret_cast<const f16x8*>(
            (const void*)(pWp + ((size_t)(kt * 8 + nt0 + 1) * 512) + l * 8));
        acc0 = __builtin_amdgcn_mfma_f32_16x16x32_f16(A, B0, acc0, 0, 0, 0);
        acc1 = __builtin_amdgcn_mfma_f32_16x16x32_f16(A, B1, acc1, 0, 0, 0);
      }
#pragma unroll
      for (int j = 0; j < 4; ++j) {
        acc0[j] = fmaxf(acc0[j], 0.f);
        acc1[j] = fmaxf(acc1[j], 0.f);
      }
    }
    {
      const int rbase = (l >> 4) << 2;
#pragma unroll
      for (int j = 0; j < 4; ++j) {
        const int row = rbase + j;
        UH h0, h1;
        h0.h = __float2half_rn(acc0[j]);
        h1.h = __float2half_rn(acc1[j]);
        a.hdst[(size_t)(n0 + row) * 3 * DD + e * DD + col0] = h0.s;
        a.hdst[(size_t)(n0 + row) * 3 * DD + e * DD + col1] = h1.s;
        hs[row][col0] = h0.s;
        hs[row][col1] = h1.s;
      }
    }
    __syncthreads();
    {
      const float b0 = a.bs[col0], b1 = a.bs[col1];
      f32x4 s0 = (f32x4){b0, b0, b0, b0};
      f32x4 s1 = (f32x4){b1, b1, b1, b1};
#pragma unroll
      for (int kt = 0; kt < 4; ++kt) {
        const f16x8 A = *reinterpret_cast<const f16x8*>((const void*)&hs[lcol][kt * 32 + g8]);
        const f16x8 B0 = *reinterpret_cast<const f16x8*>(
            (const void*)(a.pWs + ((size_t)(kt * 8 + nt0) * 512) + l * 8));
        const f16x8 B1 = *reinterpret_cast<const f16x8*>(
            (const void*)(a.pWs + ((size_t)(kt * 8 + nt0 + 1) * 512) + l * 8));
        s0 = __builtin_amdgcn_mfma_f32_16x16x32_f16(A, B0, s0, 0, 0, 0);
        s1 = __builtin_amdgcn_mfma_f32_16x16x32_f16(A, B1, s1, 0, 0, 0);
      }
      const float q0 = a.q[col0], q1 = a.q[col1];
      float p[4];
#pragma unroll
      for (int j = 0; j < 4; ++j)
        p[j] = fast_tanh(s0[j]) * q0 + fast_tanh(s1[j]) * q1;
#pragma unroll
      for (int off = 1; off < 16; off <<= 1) {
#pragma unroll
        for (int j = 0; j < 4; ++j) p[j] += __shfl_xor(p[j], off, 64);
      }
      if (lcol == 0) {
        const int rbase = (l >> 4) << 2;
#pragma unroll
        for (int j = 0; j < 4; ++j) red[w][rbase + j] = p[j];
      }
    }
    __syncthreads();
    if (tid < TRR) {
      float s = red[0][tid] + red[1][tid] + red[2][tid] + red[3][tid];
#pragma unroll
      for (int off = 1; off < 16; off <<= 1) s += __shfl_xor(s, off, 64);
      if (tid == 0) atomicAdd(&a.wsum[(blockIdx.x & 63) * 4 + e], s);
    }
    __syncthreads();
  }

  // session passthrough: hbuf m=2 + fp16 copy into hs for the w-score
  {
    const float4 v0 = *reinterpret_cast<const float4*>(a.session + (size_t)(n0 + gr) * DD + gsl * 8);
    const float4 v1 = *reinterpret_cast<const float4*>(a.session + (size_t)(n0 + gr) * DD + gsl * 8 + 4);
    UH h0, h1, h2, h3, h4, h5, h6, h7;
    h0.h = __float2half_rn(v0.x); h1.h = __float2half_rn(v0.y);
    h2.h = __float2half_rn(v0.z); h3.h = __float2half_rn(v0.w);
    h4.h = __float2half_rn(v1.x); h5.h = __float2half_rn(v1.y);
    h6.h = __float2half_rn(v1.z); h7.h = __float2half_rn(v1.w);
    uint4 o;
    o.x = (uint_t)h0.s | ((uint_t)h1.s << 16);
    o.y = (uint_t)h2.s | ((uint_t)h3.s << 16);
    o.z = (uint_t)h4.s | ((uint_t)h5.s << 16);
    o.w = (uint_t)h6.s | ((uint_t)h7.s << 16);
    *reinterpret_cast<uint4*>(&hs[gr][gsl * 8]) = o;
    *reinterpret_cast<uint4*>(a.hdst + (size_t)(n0 + gr) * 3 * DD + 2 * DD + gsl * 8) = o;
  }
  __syncthreads();
  {
    const float b0 = a.bs[col0], b1 = a.bs[col1];
    f32x4 s0 = (f32x4){b0, b0, b0, b0};
    f32x4 s1 = (f32x4){b1, b1, b1, b1};
#pragma unroll
    for (int kt = 0; kt < 4; ++kt) {
      const f16x8 A = *reinterpret_cast<const f16x8*>((const void*)&hs[lcol][kt * 32 + g8]);
      const f16x8 B0 = *reinterpret_cast<const f16x8*>(
          (const void*)(a.pWs + ((size_t)(kt * 8 + nt0) * 512) + l * 8));
      const f16x8 B1 = *reinterpret_cast<const f16x8*>(
          (const void*)(a.pWs + ((size_t)(kt * 8 + nt0 + 1) * 512) + l * 8));
      s0 = __builtin_amdgcn_mfma_f32_16x16x32_f16(A, B0, s0, 0, 0, 0);
      s1 = __builtin_amdgcn_mfma_f32_16x16x32_f16(A, B1, s1, 0, 0, 0);
    }
    const float q0 = a.q[col0], q1 = a.q[col1];
    float p[4];
#pragma unroll
    for (int j = 0; j < 4; ++j)
      p[j] = fast_tanh(s0[j]) * q0 + fast_tanh(s1[j]) * q1;
#pragma unroll
    for (int off = 1; off < 16; off <<= 1) {
#pragma unroll
      for (int j = 0; j < 4; ++j) p[j] += __shfl_xor(p[j], off, 64);
    }
    if (lcol == 0) {
      const int rbase = (l >> 4) << 2;
#pragma unroll
      for (int j = 0; j < 4; ++j) red[w][rbase + j] = p[j];
    }
  }
  __syncthreads();
  if (tid < TRR) {
    float s = red[0][tid] + red[1][tid] + red[2][tid] + red[3][tid];
#pragma unroll
    for (int off = 1; off < 16; off <<= 1) s += __shfl_xor(s, off, 64);
    if (tid == 0) atomicAdd(&a.wsum[(blockIdx.x & 63) * 4 + 2], s);
  }
}

// ---------------------------------------------------------------------------
__global__ void k_beta(const float* __restrict__ wsum, float* __restrict__ beta) {
  if (threadIdx.x == 0 && blockIdx.x == 0) {
    const float invN[3] = {1.f / 51200.f, 1.f / 1024.f, 1.f / 1024.f};
    for (int g = 0; g < 3; ++g) {
      float s0 = 0.f, s1 = 0.f, s2 = 0.f;
      for (int bkt = 0; bkt < 64; ++bkt) {
        s0 += wsum[g * 256 + bkt * 4 + 0];
        s1 += wsum[g * 256 + bkt * 4 + 1];
        s2 += wsum[g * 256 + bkt * 4 + 2];
      }
      s0 *= invN[g]; s1 *= invN[g]; s2 *= invN[g];
      const float mx = fmaxf(s0, fmaxf(s1, s2));
      const float e0 = expf(s0 - mx), e1 = expf(s1 - mx), e2 = expf(s2 - mx);
      const float inv = 1.f / (e0 + e1 + e2);
      beta[g * 4 + 0] = e0 * inv;
      beta[g * 4 + 1] = e1 * inv;
      beta[g * 4 + 2] = e2 * inv;
    }
  }
}

__global__ void k_out(const ushort_t* __restrict__ h, const float* __restrict__ beta,
                      float* __restrict__ out) {
  const int idx = blockIdx.x * blockDim.x + threadIdx.x;
  const int row = idx >> 7;
  const int g = (row < 51200) ? 0 : ((row < 52224) ? 1 : 2);
  const float* bt = beta + g * 4;
  const size_t base = (size_t)idx + (size_t)row * 2 * DD;
  UH a, b, c;
  a.s = h[base]; b.s = h[base + DD]; c.s = h[base + 2 * DD];
  out[idx] = bt[0] * __half2float(a.h) + bt[1] * __half2float(b.h) +
             bt[2] * __half2float(c.h);
}

// ---------------------------------------------------------------------------

extern "C" void kernel_launch(void* const* d_in, const int* in_sizes, int n_in,
                              void* d_out, int out_size, void* d_ws, size_t ws_size,
                              hipStream_t stream) {
  const int*   item     = (const int*)  d_in[0];
  const int*   locs     = (const int*)  d_in[1];
  const int*   times    = (const int*)  d_in[2];
  const float* session  = (const float*)d_in[3];
  const float* loc_emb  = (const float*)d_in[4];
  const float* time_emb = (const float*)d_in[5];
  const float* item_emb = (const float*)d_in[6];
  const int* nb_IL = (const int*)d_in[7];
  const int* nb_TL = (const int*)d_in[8];
  const int* nb_IT = (const int*)d_in[9];
  const int* nb_LT = (const int*)d_in[10];
  const int* nb_II = (const int*)d_in[11];
  const int* nb_LI = (const int*)d_in[12];
  const int* nb_TI = (const int*)d_in[13];
  const float* W_IL = (const float*)d_in[14]; const float* b_IL = (const float*)d_in[15];
  const float* W_TL = (const float*)d_in[16]; const float* b_TL = (const float*)d_in[17];
  const float* W_IT = (const float*)d_in[18]; const float* b_IT = (const float*)d_in[19];
  const float* W_LT = (const float*)d_in[20]; const float* b_LT = (const float*)d_in[21];
  const float* W_II = (const float*)d_in[22]; const float* b_II = (const float*)d_in[23];
  const float* W_LI = (const float*)d_in[24]; const float* b_LI = (const float*)d_in[25];
  const float* W_TI = (const float*)d_in[26]; const float* b_TI = (const float*)d_in[27];
  const float* Ws_l = (const float*)d_in[28]; const float* bs_l = (const float*)d_in[29];
  const float* q_l  = (const float*)d_in[30];
  const float* Ws_t = (const float*)d_in[31]; const float* bs_t = (const float*)d_in[32];
  const float* q_t  = (const float*)d_in[33];
  const float* Ws_i = (const float*)d_in[34]; const float* bs_i = (const float*)d_in[35];
  const float* q_i  = (const float*)d_in[36];

  float* outp = (float*)d_out;

  // ws layout: wsum/beta (16KB) | packed weights (544KB) | hbuf fp16 | tables fp16
  char* wsb = (char*)d_ws;
  float* wsum  = (float*)wsb;
  float* betap = (float*)wsb + 1024;
  ushort_t* pk = (ushort_t*)(wsb + 16384);
  ushort_t* pk_II = pk;
  ushort_t* pk_TI = pk_II + 32768;
  ushort_t* pk_LI = pk_TI + 32768;
  ushort_t* pk_IL = pk_LI + 32768;
  ushort_t* pk_TL = pk_IL + 32768;
  ushort_t* pk_IT = pk_TL + 32768;
  ushort_t* pk_LT = pk_IT + 32768;
  ushort_t* pk_Wi = pk_LT + 32768;
  ushort_t* pk_Wl = pk_Wi + 16384;
  ushort_t* pk_Wt = pk_Wl + 16384;
  ushort_t* hbuf  = pk_Wt + 16384;
  ushort_t* item_h = hbuf + (size_t)53248 * 3 * DD;
  ushort_t* loc_h  = item_h + (size_t)100000 * DD;
  ushort_t* time_h = loc_h + (size_t)10000 * DD;

  hipMemsetAsync(d_ws, 0, 16384, stream);

  CvtArgs ca;
  ca.item = item_emb; ca.loc = loc_emb; ca.timet = time_emb; ca.dst = item_h;
  k_cvt3<<<dim3(7000), dim3(256), 0, stream>>>(ca);

  PackArgs pa;
  pa.src[0] = W_II; pa.src[1] = W_TI; pa.src[2] = W_LI;
  pa.src[3] = W_IL; pa.src[4] = W_TL; pa.src[5] = W_IT; pa.src[6] = W_LT;
  pa.src[7] = Ws_i; pa.src[8] = Ws_l; pa.src[9] = Ws_t;
  pa.dst = pk;
  k_pack10<<<dim3(136), dim3(256), 0, stream>>>(pa);

  ushort_t* h_items = hbuf;
  ushort_t* h_locs  = hbuf + (size_t)51200 * 3 * DD;
  ushort_t* h_times = hbuf + (size_t)52224 * 3 * DD;

  AggIArgs ia;
  ia.self_idx = item; ia.self_t = item_h;
  ia.nb[0] = nb_II; ia.nb[1] = nb_TI; ia.nb[2] = nb_LI;
  ia.emb[0] = item_h; ia.emb[1] = time_h; ia.emb[2] = loc_h;
  ia.pW[0] = pk_II; ia.pW[1] = pk_TI; ia.pW[2] = pk_LI;
  ia.bias[0] = b_II; ia.bias[1] = b_TI; ia.bias[2] = b_LI;
  ia.pWs = pk_Wi; ia.bs = bs_i; ia.q = q_i;
  ia.hdst = h_items; ia.wsum = wsum + 0;
  k_aggI<<<dim3(51200 / TRR), dim3(256), 0, stream>>>(ia);

  AggSArgs la;
  la.self_idx = locs; la.self_t = loc_h;
  la.nb[0] = nb_IL; la.nb[1] = nb_TL;
  la.emb[0] = item_h; la.emb[1] = time_h;
  la.pW[0] = pk_IL; la.pW[1] = pk_TL;
  la.bias[0] = b_IL; la.bias[1] = b_TL;
  la.pWs = pk_Wl; la.bs = bs_l; la.q = q_l;
  la.session = session;
  la.hdst = h_locs; la.wsum = wsum + 256;
  k_aggS<<<dim3(1024 / TRR), dim3(256), 0, stream>>>(la);

  AggSArgs ta;
  ta.self_idx = times; ta.self_t = time_h;
  ta.nb[0] = nb_IT; ta.nb[1] = nb_LT;
  ta.emb[0] = item_h; ta.emb[1] = loc_h;
  ta.pW[0] = pk_IT; ta.pW[1] = pk_LT;
  ta.bias[0] = b_IT; ta.bias[1] = b_LT;
  ta.pWs = pk_Wt; ta.bs = bs_t; ta.q = q_t;
  ta.session = session;
  ta.hdst = h_times; ta.wsum = wsum + 512;
  k_aggS<<<dim3(1024 / TRR), dim3(256), 0, stream>>>(ta);

  k_beta<<<dim3(1), dim3(64), 0, stream>>>(wsum, betap);
  k_out<<<dim3((53248 * 128) / 256), dim3(256), 0, stream>>>(hbuf, betap, outp);
}

// Round 6
// 141.036 us; speedup vs baseline: 22.8993x; 1.1816x over previous
//
#include <hip/hip_runtime.h>
#include <hip/hip_fp16.h>

#define DD 128
#define KK 20
#define TRR 16

typedef unsigned int uint_t;
typedef unsigned short ushort_t;
typedef _Float16 f16x8 __attribute__((ext_vector_type(8)));
typedef float f32x4 __attribute__((ext_vector_type(4)));

union U16 { uint4 u4; __half2 h2[4]; };
union UH { __half h; ushort_t s; };

__device__ __forceinline__ float fast_tanh(float x) {
  const float e = __expf(2.f * x);
  return 1.f - 2.f / (e + 1.f);
}

__device__ __forceinline__ void acc_add(U16& a, const uint4 v) {
  U16 u; u.u4 = v;
  a.h2[0] = __hadd2(a.h2[0], u.h2[0]);
  a.h2[1] = __hadd2(a.h2[1], u.h2[1]);
  a.h2[2] = __hadd2(a.h2[2], u.h2[2]);
  a.h2[3] = __hadd2(a.h2[3], u.h2[3]);
}

// ---------------------------------------------------------------------------
// k_cvt3: all three f32 tables -> contiguous fp16 region. 8 elems/thread.
// ---------------------------------------------------------------------------
struct CvtArgs {
  const float* item; const float* loc; const float* timet;
  ushort_t* dst;
};

__global__ __launch_bounds__(256)
void k_cvt3(CvtArgs a) {
  const int t = blockIdx.x * blockDim.x + threadIdx.x;  // 7000*256 = 1,792,000
  const float* src;
  if (t < 1600000) src = a.item + (size_t)t * 8;
  else if (t < 1760000) src = a.loc + ((size_t)t - 1600000) * 8;
  else src = a.timet + ((size_t)t - 1760000) * 8;
  const float4* ip = reinterpret_cast<const float4*>(src);
  const float4 x = ip[0], y = ip[1];
  UH h[8];
  h[0].h = __float2half_rn(x.x); h[1].h = __float2half_rn(x.y);
  h[2].h = __float2half_rn(x.z); h[3].h = __float2half_rn(x.w);
  h[4].h = __float2half_rn(y.x); h[5].h = __float2half_rn(y.y);
  h[6].h = __float2half_rn(y.z); h[7].h = __float2half_rn(y.w);
  uint4 o;
  o.x = (uint_t)h[0].s | ((uint_t)h[1].s << 16);
  o.y = (uint_t)h[2].s | ((uint_t)h[3].s << 16);
  o.z = (uint_t)h[4].s | ((uint_t)h[5].s << 16);
  o.w = (uint_t)h[6].s | ((uint_t)h[7].s << 16);
  reinterpret_cast<uint4*>(a.dst)[t] = o;
}

// ---------------------------------------------------------------------------
// k_pack10: all 10 weight matrices -> MFMA B-fragment order fp16.
// Fragment (kt,nt): lane l, reg j <- W[kt*32 + (l>>4)*8 + j][nt*16 + (l&15)]
// ---------------------------------------------------------------------------
struct PackArgs {
  const float* src[10];
  ushort_t* dst;
};

__global__ __launch_bounds__(256)
void k_pack10(PackArgs a) {
  const int b = blockIdx.x, tid = threadIdx.x;
  int job, tin;
  size_t doff;
  if (b < 112) {
    job = b >> 4; tin = ((b & 15) << 8) | tid;
    doff = (size_t)job * 32768;
  } else {
    job = 7 + ((b - 112) >> 3); tin = (((b - 112) & 7) << 8) | tid;
    doff = 7ull * 32768 + (size_t)(job - 7) * 16384;
  }
  const float* W = a.src[job];
  const int l = tin & 63;
  const int ktnt = tin >> 6;
  const int nt = ktnt & 7;
  const int kt = ktnt >> 3;
  const int col = nt * 16 + (l & 15);
  const int kb = kt * 32 + ((l >> 4) << 3);
  UH h[8];
#pragma unroll
  for (int j = 0; j < 8; ++j) h[j].h = __float2half_rn(W[(size_t)(kb + j) * DD + col]);
  uint4 o;
  o.x = (uint_t)h[0].s | ((uint_t)h[1].s << 16);
  o.y = (uint_t)h[2].s | ((uint_t)h[3].s << 16);
  o.z = (uint_t)h[4].s | ((uint_t)h[5].s << 16);
  o.w = (uint_t)h[6].s | ((uint_t)h[7].s << 16);
  *reinterpret_cast<uint4*>(a.dst + doff + (size_t)ktnt * 512 + l * 8) = o;
}

// ---------------------------------------------------------------------------
// k_mega: whole graph in one kernel.
//  blocks 0..63: locs group; 64..127: times group; 128..3327: items group.
//  Staging: ids -> nidx + self -> ALL edges' gathers issued concurrently
//  (II first so its L3 misses overlap TI/LI L2 hits), session (S path).
//  xs[16][520]: self | slot1 | slot2 | slot3 (aggs; h written back in place).
//  Then per edge: MFMA(x@W)+relu -> h into slot -> MFMA(h@Ws) score -> atomic.
// ---------------------------------------------------------------------------
struct MegaArgs {
  // items
  const int* item_idx; const ushort_t* item_t;
  const int* nbI[3]; const ushort_t* embI[3]; const ushort_t* pWI[3]; const float* bI[3];
  const ushort_t* pWsI; const float* bsI; const float* qI;
  ushort_t* hI; float* wsumI;
  // locs (g=0) / times (g=1)
  const int* sidx[2]; const ushort_t* st[2];
  const int* nbS[2][2]; const ushort_t* embS[2][2];
  const ushort_t* pWS[2][2]; const float* bS[2][2];
  const ushort_t* pWsS[2]; const float* bsS[2]; const float* qS[2];
  const float* session;
  ushort_t* hS[2]; float* wsumS[2];
};

__global__ __launch_bounds__(256, 4)
void k_mega(MegaArgs a) {
  __shared__ int ids[TRR];
  __shared__ int nidx[3][TRR][KK];
  __shared__ __align__(16) ushort_t xs[TRR][4 * DD + 8];   // 520: self|s1|s2|s3
  __shared__ float red[4][TRR];

  const int tid = threadIdx.x;
  const int l = tid & 63;
  const int w = tid >> 6;
  const int bid = blockIdx.x;

  const bool isS = bid < 128;
  const int g = isS ? (bid >> 6) : 0;
  const int bl = isS ? (bid & 63) : (bid - 128);
  const int n0 = bl * TRR;

  // uniform per-block pointer set (constant-indexed local arrays)
  const int* sidx;
  const ushort_t* selft;
  const int* nb_[3];
  const ushort_t* emb_[3];
  const ushort_t* pW_[3];
  const float* bias_[3];
  const ushort_t* pws; const float* bss; const float* qp;
  ushort_t* hd; float* wbase;
  if (!isS) {
    sidx = a.item_idx; selft = a.item_t;
    nb_[0] = a.nbI[0]; nb_[1] = a.nbI[1]; nb_[2] = a.nbI[2];
    emb_[0] = a.embI[0]; emb_[1] = a.embI[1]; emb_[2] = a.embI[2];
    pW_[0] = a.pWI[0]; pW_[1] = a.pWI[1]; pW_[2] = a.pWI[2];
    bias_[0] = a.bI[0]; bias_[1] = a.bI[1]; bias_[2] = a.bI[2];
    pws = a.pWsI; bss = a.bsI; qp = a.qI;
    hd = a.hI; wbase = a.wsumI;
  } else if (g == 0) {
    sidx = a.sidx[0]; selft = a.st[0];
    nb_[0] = a.nbS[0][0]; nb_[1] = a.nbS[0][1]; nb_[2] = nullptr;
    emb_[0] = a.embS[0][0]; emb_[1] = a.embS[0][1]; emb_[2] = nullptr;
    pW_[0] = a.pWS[0][0]; pW_[1] = a.pWS[0][1]; pW_[2] = nullptr;
    bias_[0] = a.bS[0][0]; bias_[1] = a.bS[0][1]; bias_[2] = nullptr;
    pws = a.pWsS[0]; bss = a.bsS[0]; qp = a.qS[0];
    hd = a.hS[0]; wbase = a.wsumS[0];
  } else {
    sidx = a.sidx[1]; selft = a.st[1];
    nb_[0] = a.nbS[1][0]; nb_[1] = a.nbS[1][1]; nb_[2] = nullptr;
    emb_[0] = a.embS[1][0]; emb_[1] = a.embS[1][1]; emb_[2] = nullptr;
    pW_[0] = a.pWS[1][0]; pW_[1] = a.pWS[1][1]; pW_[2] = nullptr;
    bias_[0] = a.bS[1][0]; bias_[1] = a.bS[1][1]; bias_[2] = nullptr;
    pws = a.pWsS[1]; bss = a.bsS[1]; qp = a.qS[1];
    hd = a.hS[1]; wbase = a.wsumS[1];
  }

  if (tid < TRR) ids[tid] = sidx[n0 + tid];
  __syncthreads();

  const int gr = tid >> 4;        // row 0..15
  const int gsl = tid & 15;       // 16B slice within a row

  // stage neighbor index lists (edge-major)
#pragma unroll
  for (int e = 0; e < 3; ++e) {
    if (nb_[e]) {
      for (int t = tid; t < TRR * KK; t += 256) {
        const int rr = t / KK, kk = t - rr * KK;
        nidx[e][rr][kk] = nb_[e][(size_t)ids[rr] * KK + kk];
      }
    }
  }
  // self half of x
  *reinterpret_cast<uint4*>(&xs[gr][gsl * 8]) =
      *reinterpret_cast<const uint4*>(selft + ((size_t)ids[gr] << 7) + gsl * 8);
  __syncthreads();

  // ---- concurrent gathers for all edges ----
  const __half2 sc = __float2half2_rn(1.f / KK);
  const __half2 z = __float2half2_rn(0.f);
  if (!isS) {
    U16 acc0, acc1, acc2;
    acc0.h2[0] = z; acc0.h2[1] = z; acc0.h2[2] = z; acc0.h2[3] = z;
    acc1 = acc0; acc2 = acc0;
#pragma unroll
    for (int kb = 0; kb < KK; kb += 4) {
      uint4 u0[4], u1[4], u2[4];
#pragma unroll
      for (int j = 0; j < 4; ++j)
        u0[j] = *reinterpret_cast<const uint4*>(emb_[0] + ((size_t)nidx[0][gr][kb + j] << 7) + gsl * 8);
#pragma unroll
      for (int j = 0; j < 4; ++j)
        u1[j] = *reinterpret_cast<const uint4*>(emb_[1] + ((size_t)nidx[1][gr][kb + j] << 7) + gsl * 8);
#pragma unroll
      for (int j = 0; j < 4; ++j)
        u2[j] = *reinterpret_cast<const uint4*>(emb_[2] + ((size_t)nidx[2][gr][kb + j] << 7) + gsl * 8);
#pragma unroll
      for (int j = 0; j < 4; ++j) {
        acc_add(acc0, u0[j]);
        acc_add(acc1, u1[j]);
        acc_add(acc2, u2[j]);
      }
    }
#pragma unroll
    for (int i = 0; i < 4; ++i) {
      acc0.h2[i] = __hmul2(acc0.h2[i], sc);
      acc1.h2[i] = __hmul2(acc1.h2[i], sc);
      acc2.h2[i] = __hmul2(acc2.h2[i], sc);
    }
    *reinterpret_cast<uint4*>(&xs[gr][1 * DD + gsl * 8]) = acc0.u4;
    *reinterpret_cast<uint4*>(&xs[gr][2 * DD + gsl * 8]) = acc1.u4;
    *reinterpret_cast<uint4*>(&xs[gr][3 * DD + gsl * 8]) = acc2.u4;
  } else {
    U16 acc0, acc1;
    acc0.h2[0] = z; acc0.h2[1] = z; acc0.h2[2] = z; acc0.h2[3] = z;
    acc1 = acc0;
#pragma unroll
    for (int kb = 0; kb < KK; kb += 5) {
      uint4 u0[5], u1[5];
#pragma unroll
      for (int j = 0; j < 5; ++j)
        u0[j] = *reinterpret_cast<const uint4*>(emb_[0] + ((size_t)nidx[0][gr][kb + j] << 7) + gsl * 8);
#pragma unroll
      for (int j = 0; j < 5; ++j)
        u1[j] = *reinterpret_cast<const uint4*>(emb_[1] + ((size_t)nidx[1][gr][kb + j] << 7) + gsl * 8);
#pragma unroll
      for (int j = 0; j < 5; ++j) {
        acc_add(acc0, u0[j]);
        acc_add(acc1, u1[j]);
      }
    }
#pragma unroll
    for (int i = 0; i < 4; ++i) {
      acc0.h2[i] = __hmul2(acc0.h2[i], sc);
      acc1.h2[i] = __hmul2(acc1.h2[i], sc);
    }
    *reinterpret_cast<uint4*>(&xs[gr][1 * DD + gsl * 8]) = acc0.u4;
    *reinterpret_cast<uint4*>(&xs[gr][2 * DD + gsl * 8]) = acc1.u4;
    // session -> slot 3 (fp16) + hbuf m=2
    const float* srow = a.session + (size_t)(n0 + gr) * DD + gsl * 8;
    const float4 v0 = *reinterpret_cast<const float4*>(srow);
    const float4 v1 = *reinterpret_cast<const float4*>(srow + 4);
    UH h0, h1, h2, h3, h4, h5, h6, h7;
    h0.h = __float2half_rn(v0.x); h1.h = __float2half_rn(v0.y);
    h2.h = __float2half_rn(v0.z); h3.h = __float2half_rn(v0.w);
    h4.h = __float2half_rn(v1.x); h5.h = __float2half_rn(v1.y);
    h6.h = __float2half_rn(v1.z); h7.h = __float2half_rn(v1.w);
    uint4 o;
    o.x = (uint_t)h0.s | ((uint_t)h1.s << 16);
    o.y = (uint_t)h2.s | ((uint_t)h3.s << 16);
    o.z = (uint_t)h4.s | ((uint_t)h5.s << 16);
    o.w = (uint_t)h6.s | ((uint_t)h7.s << 16);
    *reinterpret_cast<uint4*>(&xs[gr][3 * DD + gsl * 8]) = o;
    *reinterpret_cast<uint4*>(hd + (size_t)(n0 + gr) * 3 * DD + 2 * DD + gsl * 8) = o;
  }
  __syncthreads();

  // ---- per-edge MFMA + score ----
  const int nt0 = 2 * w;
  const int lcol = l & 15;
  const int g8 = (l >> 4) << 3;
  const int col0 = nt0 * 16 + lcol;
  const int col1 = col0 + 16;

#pragma unroll
  for (int e = 0; e < 3; ++e) {
    const bool full = (!isS) || (e < 2);
    if (full) {
      const ushort_t* pWp = pW_[e];
      const float* bp = bias_[e];
      f32x4 acc0, acc1;
      {
        const float b0 = bp[col0], b1 = bp[col1];
        acc0 = (f32x4){b0, b0, b0, b0};
        acc1 = (f32x4){b1, b1, b1, b1};
#pragma unroll
        for (int kt = 0; kt < 8; ++kt) {
          // logical k = kt*32+g8; k<128 -> self cols; k>=128 -> slot(e+1)
          const int xcol = (kt < 4) ? (kt * 32 + g8) : (e * DD + kt * 32 + g8);
          const f16x8 A = *reinterpret_cast<const f16x8*>((const void*)&xs[lcol][xcol]);
          const f16x8 B0 = *reinterpret_cast<const f16x8*>(
              (const void*)(pWp + ((size_t)(kt * 8 + nt0) * 512) + l * 8));
          const f16x8 B1 = *reinterpret_cast<const f16x8*>(
              (const void*)(pWp + ((size_t)(kt * 8 + nt0 + 1) * 512) + l * 8));
          acc0 = __builtin_amdgcn_mfma_f32_16x16x32_f16(A, B0, acc0, 0, 0, 0);
          acc1 = __builtin_amdgcn_mfma_f32_16x16x32_f16(A, B1, acc1, 0, 0, 0);
        }
#pragma unroll
        for (int j = 0; j < 4; ++j) {
          acc0[j] = fmaxf(acc0[j], 0.f);
          acc1[j] = fmaxf(acc1[j], 0.f);
        }
      }
      __syncthreads();  // all A-reads of slot e+1 done before overwrite
      {
        const int rbase = (l >> 4) << 2;
#pragma unroll
        for (int j = 0; j < 4; ++j) {
          const int row = rbase + j;
          UH h0, h1;
          h0.h = __float2half_rn(acc0[j]);
          h1.h = __float2half_rn(acc1[j]);
          hd[(size_t)(n0 + row) * 3 * DD + e * DD + col0] = h0.s;
          hd[(size_t)(n0 + row) * 3 * DD + e * DD + col1] = h1.s;
          xs[row][(e + 1) * DD + col0] = h0.s;
          xs[row][(e + 1) * DD + col1] = h1.s;
        }
      }
      __syncthreads();  // h visible in LDS
    }
    // score: t = h @ Ws + bs; w = sum_cols tanh(t)*q  (h in slot e+1)
    {
      const float b0 = bss[col0], b1 = bss[col1];
      f32x4 s0 = (f32x4){b0, b0, b0, b0};
      f32x4 s1 = (f32x4){b1, b1, b1, b1};
#pragma unroll
      for (int kt = 0; kt < 4; ++kt) {
        const f16x8 A = *reinterpret_cast<const f16x8*>(
            (const void*)&xs[lcol][(e + 1) * DD + kt * 32 + g8]);
        const f16x8 B0 = *reinterpret_cast<const f16x8*>(
            (const void*)(pws + ((size_t)(kt * 8 + nt0) * 512) + l * 8));
        const f16x8 B1 = *reinterpret_cast<const f16x8*>(
            (const void*)(pws + ((size_t)(kt * 8 + nt0 + 1) * 512) + l * 8));
        s0 = __builtin_amdgcn_mfma_f32_16x16x32_f16(A, B0, s0, 0, 0, 0);
        s1 = __builtin_amdgcn_mfma_f32_16x16x32_f16(A, B1, s1, 0, 0, 0);
      }
      const float q0 = qp[col0], q1 = qp[col1];
      float p[4];
#pragma unroll
      for (int j = 0; j < 4; ++j)
        p[j] = fast_tanh(s0[j]) * q0 + fast_tanh(s1[j]) * q1;
#pragma unroll
      for (int off = 1; off < 16; off <<= 1) {
#pragma unroll
        for (int j = 0; j < 4; ++j) p[j] += __shfl_xor(p[j], off, 64);
      }
      if (lcol == 0) {
        const int rbase = (l >> 4) << 2;
#pragma unroll
        for (int j = 0; j < 4; ++j) red[w][rbase + j] = p[j];
      }
    }
    __syncthreads();
    if (tid < TRR) {
      float s = red[0][tid] + red[1][tid] + red[2][tid] + red[3][tid];
#pragma unroll
      for (int off = 1; off < 16; off <<= 1) s += __shfl_xor(s, off, 64);
      if (tid == 0) atomicAdd(&wbase[(bl & 63) * 4 + e], s);
    }
    __syncthreads();  // red reuse guard for next edge
  }
}

// ---------------------------------------------------------------------------
__global__ void k_beta(const float* __restrict__ wsum, float* __restrict__ beta) {
  if (threadIdx.x == 0 && blockIdx.x == 0) {
    const float invN[3] = {1.f / 51200.f, 1.f / 1024.f, 1.f / 1024.f};
    for (int g = 0; g < 3; ++g) {
      float s0 = 0.f, s1 = 0.f, s2 = 0.f;
      for (int bkt = 0; bkt < 64; ++bkt) {
        s0 += wsum[g * 256 + bkt * 4 + 0];
        s1 += wsum[g * 256 + bkt * 4 + 1];
        s2 += wsum[g * 256 + bkt * 4 + 2];
      }
      s0 *= invN[g]; s1 *= invN[g]; s2 *= invN[g];
      const float mx = fmaxf(s0, fmaxf(s1, s2));
      const float e0 = expf(s0 - mx), e1 = expf(s1 - mx), e2 = expf(s2 - mx);
      const float inv = 1.f / (e0 + e1 + e2);
      beta[g * 4 + 0] = e0 * inv;
      beta[g * 4 + 1] = e1 * inv;
      beta[g * 4 + 2] = e2 * inv;
    }
  }
}

__global__ void k_out(const ushort_t* __restrict__ h, const float* __restrict__ beta,
                      float* __restrict__ out) {
  const int idx = blockIdx.x * blockDim.x + threadIdx.x;
  const int row = idx >> 7;
  const int g = (row < 51200) ? 0 : ((row < 52224) ? 1 : 2);
  const float* bt = beta + g * 4;
  const size_t base = (size_t)idx + (size_t)row * 2 * DD;
  UH a, b, c;
  a.s = h[base]; b.s = h[base + DD]; c.s = h[base + 2 * DD];
  out[idx] = bt[0] * __half2float(a.h) + bt[1] * __half2float(b.h) +
             bt[2] * __half2float(c.h);
}

// ---------------------------------------------------------------------------

extern "C" void kernel_launch(void* const* d_in, const int* in_sizes, int n_in,
                              void* d_out, int out_size, void* d_ws, size_t ws_size,
                              hipStream_t stream) {
  const int*   item     = (const int*)  d_in[0];
  const int*   locs     = (const int*)  d_in[1];
  const int*   times    = (const int*)  d_in[2];
  const float* session  = (const float*)d_in[3];
  const float* loc_emb  = (const float*)d_in[4];
  const float* time_emb = (const float*)d_in[5];
  const float* item_emb = (const float*)d_in[6];
  const int* nb_IL = (const int*)d_in[7];
  const int* nb_TL = (const int*)d_in[8];
  const int* nb_IT = (const int*)d_in[9];
  const int* nb_LT = (const int*)d_in[10];
  const int* nb_II = (const int*)d_in[11];
  const int* nb_LI = (const int*)d_in[12];
  const int* nb_TI = (const int*)d_in[13];
  const float* W_IL = (const float*)d_in[14]; const float* b_IL = (const float*)d_in[15];
  const float* W_TL = (const float*)d_in[16]; const float* b_TL = (const float*)d_in[17];
  const float* W_IT = (const float*)d_in[18]; const float* b_IT = (const float*)d_in[19];
  const float* W_LT = (const float*)d_in[20]; const float* b_LT = (const float*)d_in[21];
  const float* W_II = (const float*)d_in[22]; const float* b_II = (const float*)d_in[23];
  const float* W_LI = (const float*)d_in[24]; const float* b_LI = (const float*)d_in[25];
  const float* W_TI = (const float*)d_in[26]; const float* b_TI = (const float*)d_in[27];
  const float* Ws_l = (const float*)d_in[28]; const float* bs_l = (const float*)d_in[29];
  const float* q_l  = (const float*)d_in[30];
  const float* Ws_t = (const float*)d_in[31]; const float* bs_t = (const float*)d_in[32];
  const float* q_t  = (const float*)d_in[33];
  const float* Ws_i = (const float*)d_in[34]; const float* bs_i = (const float*)d_in[35];
  const float* q_i  = (const float*)d_in[36];

  float* outp = (float*)d_out;

  // ws layout: wsum/beta (16KB) | packed weights (544KB) | hbuf fp16 | tables fp16
  char* wsb = (char*)d_ws;
  float* wsum  = (float*)wsb;
  float* betap = (float*)wsb + 1024;
  ushort_t* pk = (ushort_t*)(wsb + 16384);
  ushort_t* pk_II = pk;
  ushort_t* pk_TI = pk_II + 32768;
  ushort_t* pk_LI = pk_TI + 32768;
  ushort_t* pk_IL = pk_LI + 32768;
  ushort_t* pk_TL = pk_IL + 32768;
  ushort_t* pk_IT = pk_TL + 32768;
  ushort_t* pk_LT = pk_IT + 32768;
  ushort_t* pk_Wi = pk_LT + 32768;
  ushort_t* pk_Wl = pk_Wi + 16384;
  ushort_t* pk_Wt = pk_Wl + 16384;
  ushort_t* hbuf  = pk_Wt + 16384;
  ushort_t* item_h = hbuf + (size_t)53248 * 3 * DD;
  ushort_t* loc_h  = item_h + (size_t)100000 * DD;
  ushort_t* time_h = loc_h + (size_t)10000 * DD;

  hipMemsetAsync(d_ws, 0, 16384, stream);

  CvtArgs ca;
  ca.item = item_emb; ca.loc = loc_emb; ca.timet = time_emb; ca.dst = item_h;
  k_cvt3<<<dim3(7000), dim3(256), 0, stream>>>(ca);

  PackArgs pa;
  pa.src[0] = W_II; pa.src[1] = W_TI; pa.src[2] = W_LI;
  pa.src[3] = W_IL; pa.src[4] = W_TL; pa.src[5] = W_IT; pa.src[6] = W_LT;
  pa.src[7] = Ws_i; pa.src[8] = Ws_l; pa.src[9] = Ws_t;
  pa.dst = pk;
  k_pack10<<<dim3(136), dim3(256), 0, stream>>>(pa);

  ushort_t* h_items = hbuf;
  ushort_t* h_locs  = hbuf + (size_t)51200 * 3 * DD;
  ushort_t* h_times = hbuf + (size_t)52224 * 3 * DD;

  MegaArgs ma;
  ma.item_idx = item; ma.item_t = item_h;
  ma.nbI[0] = nb_II; ma.nbI[1] = nb_TI; ma.nbI[2] = nb_LI;
  ma.embI[0] = item_h; ma.embI[1] = time_h; ma.embI[2] = loc_h;
  ma.pWI[0] = pk_II; ma.pWI[1] = pk_TI; ma.pWI[2] = pk_LI;
  ma.bI[0] = b_II; ma.bI[1] = b_TI; ma.bI[2] = b_LI;
  ma.pWsI = pk_Wi; ma.bsI = bs_i; ma.qI = q_i;
  ma.hI = h_items; ma.wsumI = wsum + 0;
  ma.sidx[0] = locs;  ma.sidx[1] = times;
  ma.st[0] = loc_h;   ma.st[1] = time_h;
  ma.nbS[0][0] = nb_IL; ma.nbS[0][1] = nb_TL;
  ma.nbS[1][0] = nb_IT; ma.nbS[1][1] = nb_LT;
  ma.embS[0][0] = item_h; ma.embS[0][1] = time_h;
  ma.embS[1][0] = item_h; ma.embS[1][1] = loc_h;
  ma.pWS[0][0] = pk_IL; ma.pWS[0][1] = pk_TL;
  ma.pWS[1][0] = pk_IT; ma.pWS[1][1] = pk_LT;
  ma.bS[0][0] = b_IL; ma.bS[0][1] = b_TL;
  ma.bS[1][0] = b_IT; ma.bS[1][1] = b_LT;
  ma.pWsS[0] = pk_Wl; ma.pWsS[1] = pk_Wt;
  ma.bsS[0] = bs_l; ma.bsS[1] = bs_t;
  ma.qS[0] = q_l; ma.qS[1] = q_t;
  ma.session = session;
  ma.hS[0] = h_locs; ma.hS[1] = h_times;
  ma.wsumS[0] = wsum + 256; ma.wsumS[1] = wsum + 512;
  k_mega<<<dim3(128 + 51200 / TRR), dim3(256), 0, stream>>>(ma);

  k_beta<<<dim3(1), dim3(64), 0, stream>>>(wsum, betap);
  k_out<<<dim3((53248 * 128) / 256), dim3(256), 0, stream>>>(hbuf, betap, outp);
}